// Round 2
// baseline (7768.050 us; speedup 1.0000x reference)
//
#include <hip/hip_runtime.h>
#include <hip/hip_bf16.h>

#define B_ 4
#define N_ 1569
#define IND 768
#define HEADS_ 12
#define HD_ 64
#define T0_ 8
#define H0_ 14
#define W0_ 14
#define M_ (B_*N_)          // 6276
#define QKVD (3*IND)        // 2304

typedef __attribute__((ext_vector_type(8))) float float8;

// ---------------- GEMM: C[M,Nc] = A[M,K] * Bw[K,Nc] + bias ----------------
// 128x128 tile, BK=16, 256 threads, 8x8 outputs per thread, f32 accumulate.
__global__ __launch_bounds__(256) void gemm_bias(
        const float* __restrict__ A, const float* __restrict__ Bw,
        const float* __restrict__ bias, float* __restrict__ C,
        int M, int K, int Nc) {
    __shared__ __align__(16) float As[16][132];
    __shared__ __align__(16) float Bs[16][132];
    const int tid = threadIdx.x;
    const int bn = blockIdx.x * 128;
    const int bm = blockIdx.y * 128;
    const int arow = tid >> 1, ak0 = (tid & 1) * 8;   // A tile: 128 rows x 16 k
    const int brow = tid >> 4, bn0 = (tid & 15) * 8;  // B tile: 16 k x 128 cols
    const int ty = tid >> 4, tx = tid & 15;

    float acc[8][8];
    #pragma unroll
    for (int i = 0; i < 8; i++)
        #pragma unroll
        for (int j = 0; j < 8; j++) acc[i][j] = 0.f;

    for (int kt = 0; kt < K; kt += 16) {
        float av[8];
        if (bm + arow < M) {
            const float* p = A + (size_t)(bm + arow) * K + kt + ak0;
            float8 v = *reinterpret_cast<const float8*>(p);
            #pragma unroll
            for (int j = 0; j < 8; j++) av[j] = v[j];
        } else {
            #pragma unroll
            for (int j = 0; j < 8; j++) av[j] = 0.f;
        }
        const float* pb = Bw + (size_t)(kt + brow) * Nc + bn + bn0;
        float8 bv = *reinterpret_cast<const float8*>(pb);

        __syncthreads();   // previous compute done before overwriting LDS
        #pragma unroll
        for (int j = 0; j < 8; j++) As[ak0 + j][arow] = av[j];
        #pragma unroll
        for (int j = 0; j < 8; j++) Bs[brow][bn0 + j] = bv[j];
        __syncthreads();

        #pragma unroll
        for (int k = 0; k < 16; k++) {
            const float4* ap = reinterpret_cast<const float4*>(&As[k][ty * 8]);
            const float4* bp = reinterpret_cast<const float4*>(&Bs[k][tx * 8]);
            float4 a0 = ap[0], a1 = ap[1], b0 = bp[0], b1 = bp[1];
            float a[8] = {a0.x, a0.y, a0.z, a0.w, a1.x, a1.y, a1.z, a1.w};
            float b[8] = {b0.x, b0.y, b0.z, b0.w, b1.x, b1.y, b1.z, b1.w};
            #pragma unroll
            for (int i = 0; i < 8; i++)
                #pragma unroll
                for (int j = 0; j < 8; j++) acc[i][j] += a[i] * b[j];
        }
    }

    float bcol[8];
    #pragma unroll
    for (int j = 0; j < 8; j++) bcol[j] = bias[bn + tx * 8 + j];
    #pragma unroll
    for (int i = 0; i < 8; i++) {
        int r = bm + ty * 8 + i;
        if (r >= M) continue;
        float4 o0 = {acc[i][0] + bcol[0], acc[i][1] + bcol[1], acc[i][2] + bcol[2], acc[i][3] + bcol[3]};
        float4 o1 = {acc[i][4] + bcol[4], acc[i][5] + bcol[5], acc[i][6] + bcol[6], acc[i][7] + bcol[7]};
        float* cp = C + (size_t)r * Nc + bn + tx * 8;
        *reinterpret_cast<float4*>(cp) = o0;
        *reinterpret_cast<float4*>(cp + 4) = o1;
    }
}

// ---------------- depthwise 3x3x3 conv pool + LayerNorm(64) ----------------
// grid: 3 * B * HEADS * N blocks of 64 threads (one wave). s = q/k/v.
__global__ __launch_bounds__(64) void pool_ln(
        const float* __restrict__ qkv,
        const float* __restrict__ kq, const float* __restrict__ kk,
        const float* __restrict__ kv,
        const float* __restrict__ nqw, const float* __restrict__ nqb,
        const float* __restrict__ nkw, const float* __restrict__ nkb,
        const float* __restrict__ nvw, const float* __restrict__ nvb,
        float* __restrict__ pq, float* __restrict__ pk, float* __restrict__ pv) {
    const int d = threadIdx.x;
    int bid = blockIdx.x;
    const int n = bid % N_; bid /= N_;
    const int head = bid % HEADS_; bid /= HEADS_;
    const int b = bid % B_;
    const int s = bid / B_;

    const float* kern = (s == 0) ? kq : ((s == 1) ? kk : kv);
    const float* lw = (s == 0) ? nqw : ((s == 1) ? nkw : nvw);
    const float* lb = (s == 0) ? nqb : ((s == 1) ? nkb : nvb);
    float* dst = (s == 0) ? pq : ((s == 1) ? pk : pv);

    const size_t colbase = (size_t)s * IND + head * HD_ + d;
    float y;
    if (n == 0) {
        y = qkv[(size_t)(b * N_) * QKVD + colbase];
    } else {
        const int m = n - 1;
        const int ti = m / (H0_ * W0_);
        const int rr = m % (H0_ * W0_);
        const int hi = rr / W0_, wi = rr % W0_;
        float acc = 0.f;
        #pragma unroll
        for (int kt = 0; kt < 3; kt++) {
            int t2 = ti + kt - 1;
            if (t2 < 0 || t2 >= T0_) continue;
            #pragma unroll
            for (int kh = 0; kh < 3; kh++) {
                int h2 = hi + kh - 1;
                if (h2 < 0 || h2 >= H0_) continue;
                #pragma unroll
                for (int kw = 0; kw < 3; kw++) {
                    int w2 = wi + kw - 1;
                    if (w2 < 0 || w2 >= W0_) continue;
                    int node = 1 + (t2 * H0_ + h2) * W0_ + w2;
                    float xv = qkv[(size_t)(b * N_ + node) * QKVD + colbase];
                    float kvv = kern[d * 27 + (kt * 3 + kh) * 3 + kw];
                    acc += xv * kvv;
                }
            }
        }
        y = acc;
    }
    // LayerNorm over the 64 channels = the one wave
    float s1 = y;
    #pragma unroll
    for (int o = 32; o > 0; o >>= 1) s1 += __shfl_xor(s1, o);
    float mu = s1 * (1.f / 64.f);
    float diff = y - mu;
    float s2 = diff * diff;
    #pragma unroll
    for (int o = 32; o > 0; o >>= 1) s2 += __shfl_xor(s2, o);
    float var = s2 * (1.f / 64.f);
    float out = diff * rsqrtf(var + 1e-5f) * lw[d] + lb[d];
    dst[((size_t)((b * HEADS_ + head) * N_) + n) * HD_ + d] = out;
}

// ---------------- attention: one block per (b, head, query row) ----------------
__global__ __launch_bounds__(256) void attn_kernel(
        const float* __restrict__ pq, const float* __restrict__ pk, const float* __restrict__ pv,
        const float* __restrict__ rpt, const float* __restrict__ rph,
        const float* __restrict__ rpw, float* __restrict__ aout) {
    __shared__ __align__(16) float qs[64];
    __shared__ float relT[T0_], relH[H0_], relW[W0_];
    __shared__ float sc[N_];
    __shared__ float red[256];
    const int tid = threadIdx.x;
    int bid = blockIdx.x;
    const int qi = bid % N_; bid /= N_;
    const int h = bid % HEADS_;
    const int b = bid / HEADS_;

    const float* Q = pq + ((size_t)((b * HEADS_ + h) * N_) + qi) * HD_;
    const float* K = pk + (size_t)((b * HEADS_ + h) * N_) * HD_;
    const float* V = pv + (size_t)((b * HEADS_ + h) * N_) * HD_;

    if (tid < 64) qs[tid] = Q[tid];
    __syncthreads();

    if (qi > 0 && tid < 36) {
        const int m = qi - 1;
        const int ti = m / (H0_ * W0_);
        const int rr = m % (H0_ * W0_);
        const int hi = rr / W0_, wi = rr % W0_;
        const float* rp;
        float* dstp;
        if (tid < 8)       { rp = rpt + (size_t)(ti - tid + (T0_ - 1)) * HD_;        dstp = &relT[tid]; }
        else if (tid < 22) { int hj = tid - 8;  rp = rph + (size_t)(hi - hj + (H0_ - 1)) * HD_; dstp = &relH[hj]; }
        else               { int wj = tid - 22; rp = rpw + (size_t)(wi - wj + (W0_ - 1)) * HD_; dstp = &relW[wj]; }
        float acc = 0.f;
        for (int dd = 0; dd < 64; dd++) acc += qs[dd] * rp[dd];
        *dstp = acc;
    }
    __syncthreads();

    // pass 1: scores + max
    const float4* q4 = reinterpret_cast<const float4*>(qs);
    float lmax = -1e30f;
    for (int j = tid; j < N_; j += 256) {
        const float4* kr = reinterpret_cast<const float4*>(K + (size_t)j * HD_);
        float acc = 0.f;
        #pragma unroll
        for (int dd = 0; dd < 16; dd++) {
            float4 kv4 = kr[dd];
            float4 qv = q4[dd];
            acc += kv4.x * qv.x + kv4.y * qv.y + kv4.z * qv.z + kv4.w * qv.w;
        }
        acc *= 0.125f;
        if (qi > 0 && j > 0) {
            int mj = j - 1;
            int tj = mj / (H0_ * W0_);
            int rj = mj % (H0_ * W0_);
            acc += relT[tj] + relH[rj / W0_] + relW[rj % W0_];
        }
        sc[j] = acc;
        lmax = fmaxf(lmax, acc);
    }
    red[tid] = lmax; __syncthreads();
    for (int ss = 128; ss > 0; ss >>= 1) {
        if (tid < ss) red[tid] = fmaxf(red[tid], red[tid + ss]);
        __syncthreads();
    }
    const float mx = red[0];
    __syncthreads();

    // pass 2: exp + sum
    float lsum = 0.f;
    for (int j = tid; j < N_; j += 256) {
        float e = __expf(sc[j] - mx);
        sc[j] = e;
        lsum += e;
    }
    red[tid] = lsum; __syncthreads();
    for (int ss = 128; ss > 0; ss >>= 1) {
        if (tid < ss) red[tid] += red[tid + ss];
        __syncthreads();
    }
    const float ssum = red[0];

    // pass 3: PV, threads = (d, quarter)
    const int d = tid & 63, part = tid >> 6;
    float acc = 0.f;
    for (int j = part; j < N_; j += 4) acc += sc[j] * V[(size_t)j * HD_ + d];
    __syncthreads();           // done reading red[0]
    red[tid] = acc; __syncthreads();
    if (tid < 64) {
        float o = red[tid] + red[tid + 64] + red[tid + 128] + red[tid + 192];
        o /= ssum;
        if (qi > 0) o += qs[tid];       // residual +pooled q
        aout[(size_t)(b * N_ + qi) * (HEADS_ * HD_) + h * HD_ + tid] = o;
    }
}

extern "C" void kernel_launch(void* const* d_in, const int* in_sizes, int n_in,
                              void* d_out, int out_size, void* d_ws, size_t ws_size,
                              hipStream_t stream) {
    const float* x    = (const float*)d_in[0];
    const float* Wqkv = (const float*)d_in[1];
    const float* bqkv = (const float*)d_in[2];
    const float* kq   = (const float*)d_in[3];
    const float* kk   = (const float*)d_in[4];
    const float* kv   = (const float*)d_in[5];
    const float* nqw  = (const float*)d_in[6];
    const float* nqb  = (const float*)d_in[7];
    const float* nkw  = (const float*)d_in[8];
    const float* nkb  = (const float*)d_in[9];
    const float* nvw  = (const float*)d_in[10];
    const float* nvb  = (const float*)d_in[11];
    const float* rpt  = (const float*)d_in[12];
    const float* rph  = (const float*)d_in[13];
    const float* rpw  = (const float*)d_in[14];
    const float* Wproj= (const float*)d_in[15];
    const float* bproj= (const float*)d_in[16];
    float* out = (float*)d_out;

    const size_t qkv_elems  = (size_t)M_ * QKVD;                  // 14,459,904 f32
    const size_t pool_elems = (size_t)B_ * HEADS_ * N_ * HD_;     //  4,819,968 f32
    float* qkvp = (float*)d_ws;
    float* pq   = qkvp + qkv_elems;
    float* pk   = pq + pool_elems;
    float* pv   = pk + pool_elems;
    float* aout = qkvp;    // alias: qkv scratch is dead once pool_ln is done
                           // total ws = (14.46M + 3*4.82M)*4B ≈ 116 MB

    dim3 g1(QKVD / 128, (M_ + 127) / 128);
    gemm_bias<<<g1, 256, 0, stream>>>(x, Wqkv, bqkv, qkvp, M_, IND, QKVD);

    pool_ln<<<3 * B_ * HEADS_ * N_, 64, 0, stream>>>(qkvp, kq, kk, kv,
        nqw, nqb, nkw, nkb, nvw, nvb, pq, pk, pv);

    attn_kernel<<<B_ * HEADS_ * N_, 256, 0, stream>>>(pq, pk, pv, rpt, rph, rpw, aout);

    dim3 g2((HEADS_ * HD_) / 128, (M_ + 127) / 128);
    gemm_bias<<<g2, 256, 0, stream>>>(aout, Wproj, bproj, out, M_, IND, HEADS_ * HD_);
}

// Round 3
// 1422.277 us; speedup vs baseline: 5.4617x; 5.4617x over previous
//
#include <hip/hip_runtime.h>
#include <hip/hip_bf16.h>

#define B_ 4
#define N_ 1569
#define IND 768
#define HEADS_ 12
#define HD_ 64
#define T0_ 8
#define H0_ 14
#define W0_ 14
#define M_ (B_*N_)          // 6276
#define QKVD (3*IND)        // 2304
#define NKT 25              // ceil(1569/64) key/query tiles

typedef __attribute__((ext_vector_type(8))) float float8;

// ---------------- GEMM: C[M,Nc] = A[M,K] * Bw[K,Nc] + bias ----------------
__global__ __launch_bounds__(256) void gemm_bias(
        const float* __restrict__ A, const float* __restrict__ Bw,
        const float* __restrict__ bias, float* __restrict__ C,
        int M, int K, int Nc) {
    __shared__ __align__(16) float As[16][132];
    __shared__ __align__(16) float Bs[16][132];
    const int tid = threadIdx.x;
    const int bn = blockIdx.x * 128;
    const int bm = blockIdx.y * 128;
    const int arow = tid >> 1, ak0 = (tid & 1) * 8;
    const int brow = tid >> 4, bn0 = (tid & 15) * 8;
    const int ty = tid >> 4, tx = tid & 15;

    float acc[8][8];
    #pragma unroll
    for (int i = 0; i < 8; i++)
        #pragma unroll
        for (int j = 0; j < 8; j++) acc[i][j] = 0.f;

    for (int kt = 0; kt < K; kt += 16) {
        float av[8];
        if (bm + arow < M) {
            const float* p = A + (size_t)(bm + arow) * K + kt + ak0;
            float8 v = *reinterpret_cast<const float8*>(p);
            #pragma unroll
            for (int j = 0; j < 8; j++) av[j] = v[j];
        } else {
            #pragma unroll
            for (int j = 0; j < 8; j++) av[j] = 0.f;
        }
        const float* pb = Bw + (size_t)(kt + brow) * Nc + bn + bn0;
        float8 bv = *reinterpret_cast<const float8*>(pb);

        __syncthreads();
        #pragma unroll
        for (int j = 0; j < 8; j++) As[ak0 + j][arow] = av[j];
        #pragma unroll
        for (int j = 0; j < 8; j++) Bs[brow][bn0 + j] = bv[j];
        __syncthreads();

        #pragma unroll
        for (int k = 0; k < 16; k++) {
            const float4* ap = reinterpret_cast<const float4*>(&As[k][ty * 8]);
            const float4* bp = reinterpret_cast<const float4*>(&Bs[k][tx * 8]);
            float4 a0 = ap[0], a1 = ap[1], b0 = bp[0], b1 = bp[1];
            float a[8] = {a0.x, a0.y, a0.z, a0.w, a1.x, a1.y, a1.z, a1.w};
            float b[8] = {b0.x, b0.y, b0.z, b0.w, b1.x, b1.y, b1.z, b1.w};
            #pragma unroll
            for (int i = 0; i < 8; i++)
                #pragma unroll
                for (int j = 0; j < 8; j++) acc[i][j] += a[i] * b[j];
        }
    }

    float bcol[8];
    #pragma unroll
    for (int j = 0; j < 8; j++) bcol[j] = bias[bn + tx * 8 + j];
    #pragma unroll
    for (int i = 0; i < 8; i++) {
        int r = bm + ty * 8 + i;
        if (r >= M) continue;
        float4 o0 = {acc[i][0] + bcol[0], acc[i][1] + bcol[1], acc[i][2] + bcol[2], acc[i][3] + bcol[3]};
        float4 o1 = {acc[i][4] + bcol[4], acc[i][5] + bcol[5], acc[i][6] + bcol[6], acc[i][7] + bcol[7]};
        float* cp = C + (size_t)r * Nc + bn + tx * 8;
        *reinterpret_cast<float4*>(cp) = o0;
        *reinterpret_cast<float4*>(cp + 4) = o1;
    }
}

// ---------------- depthwise 3x3x3 conv pool + LayerNorm(64) ----------------
__global__ __launch_bounds__(64) void pool_ln(
        const float* __restrict__ qkv,
        const float* __restrict__ kq, const float* __restrict__ kk,
        const float* __restrict__ kv,
        const float* __restrict__ nqw, const float* __restrict__ nqb,
        const float* __restrict__ nkw, const float* __restrict__ nkb,
        const float* __restrict__ nvw, const float* __restrict__ nvb,
        float* __restrict__ pq, float* __restrict__ pk, float* __restrict__ pv) {
    const int d = threadIdx.x;
    int bid = blockIdx.x;
    const int n = bid % N_; bid /= N_;
    const int head = bid % HEADS_; bid /= HEADS_;
    const int b = bid % B_;
    const int s = bid / B_;

    const float* kern = (s == 0) ? kq : ((s == 1) ? kk : kv);
    const float* lw = (s == 0) ? nqw : ((s == 1) ? nkw : nvw);
    const float* lb = (s == 0) ? nqb : ((s == 1) ? nkb : nvb);
    float* dst = (s == 0) ? pq : ((s == 1) ? pk : pv);

    const size_t colbase = (size_t)s * IND + head * HD_ + d;
    float y;
    if (n == 0) {
        y = qkv[(size_t)(b * N_) * QKVD + colbase];
    } else {
        const int m = n - 1;
        const int ti = m / (H0_ * W0_);
        const int rr = m % (H0_ * W0_);
        const int hi = rr / W0_, wi = rr % W0_;
        float acc = 0.f;
        #pragma unroll
        for (int kt = 0; kt < 3; kt++) {
            int t2 = ti + kt - 1;
            if (t2 < 0 || t2 >= T0_) continue;
            #pragma unroll
            for (int kh = 0; kh < 3; kh++) {
                int h2 = hi + kh - 1;
                if (h2 < 0 || h2 >= H0_) continue;
                #pragma unroll
                for (int kw = 0; kw < 3; kw++) {
                    int w2 = wi + kw - 1;
                    if (w2 < 0 || w2 >= W0_) continue;
                    int node = 1 + (t2 * H0_ + h2) * W0_ + w2;
                    float xv = qkv[(size_t)(b * N_ + node) * QKVD + colbase];
                    float kvv = kern[d * 27 + (kt * 3 + kh) * 3 + kw];
                    acc += xv * kvv;
                }
            }
        }
        y = acc;
    }
    float s1 = y;
    #pragma unroll
    for (int o = 32; o > 0; o >>= 1) s1 += __shfl_xor(s1, o);
    float mu = s1 * (1.f / 64.f);
    float diff = y - mu;
    float s2 = diff * diff;
    #pragma unroll
    for (int o = 32; o > 0; o >>= 1) s2 += __shfl_xor(s2, o);
    float var = s2 * (1.f / 64.f);
    float out = diff * rsqrtf(var + 1e-5f) * lw[d] + lb[d];
    dst[((size_t)((b * HEADS_ + head) * N_) + n) * HD_ + d] = out;
}

// ---------------- flash attention: 64-query tile per block ----------------
// 256 threads as 16(r: row-groups of 4) x 16(c: col/dim-groups of 4).
// LDS row stride 68 floats: rows stay 16B-aligned; hot reads <=2-way bank alias.
__global__ __launch_bounds__(256) void attn_flash(
        const float* __restrict__ pq, const float* __restrict__ pk, const float* __restrict__ pv,
        const float* __restrict__ rpt, const float* __restrict__ rph,
        const float* __restrict__ rpw, float* __restrict__ aout) {
    __shared__ __align__(16) float QT[64][68];   // [d][qrow]  (Q transposed)
    __shared__ __align__(16) float KT[64][68];   // [d][kcol]  (K transposed)
    __shared__ __align__(16) float Vs[64][68];   // [krow][d]  (V natural)
    __shared__ __align__(16) float Ps[64][68];   // [qrow][kcol]
    __shared__ float relT[64][8];
    __shared__ float relH[64][14];
    __shared__ float relW[64][14];

    const int tid = threadIdx.x;
    int bid = blockIdx.x;
    const int qt = bid % NKT; bid /= NKT;
    const int h = bid % HEADS_;
    const int b = bid / HEADS_;
    const int q0 = qt * 64;

    const size_t bh = (size_t)((b * HEADS_ + h) * N_) * HD_;
    const float* Qg = pq + bh;
    const float* Kg = pk + bh;
    const float* Vg = pv + bh;

    // ---- stage Q^T ----
    {
        const int row = tid >> 2, mm = tid & 3;
        const int qi = q0 + row;
        float buf[16];
        if (qi < N_) {
            const float4* s = reinterpret_cast<const float4*>(Qg + (size_t)qi * HD_ + mm * 16);
            *reinterpret_cast<float4*>(&buf[0])  = s[0];
            *reinterpret_cast<float4*>(&buf[4])  = s[1];
            *reinterpret_cast<float4*>(&buf[8])  = s[2];
            *reinterpret_cast<float4*>(&buf[12]) = s[3];
        } else {
            #pragma unroll
            for (int ii = 0; ii < 16; ii++) buf[ii] = 0.f;
        }
        const int d0 = mm * 16;
        #pragma unroll
        for (int ii = 0; ii < 16; ii++) QT[d0 + ii][row] = buf[ii];
    }
    __syncthreads();

    // ---- rel-pos dot tables: relX[qrow][idx] = dot(q_row, rel_table_row) ----
    #pragma unroll
    for (int it = 0; it < 9; it++) {           // 9*256 = 2304 = 64*36
        int flat = it * 256 + tid;
        int row = flat / 36, idx = flat - row * 36;
        int qi = q0 + row;
        bool valid = (qi >= 1 && qi < N_);
        int m = valid ? (qi - 1) : 0;
        int ti = m / 196, rr2 = m - ti * 196;
        int hi = rr2 / 14, wi = rr2 - hi * 14;
        const float* tab;
        float* dst;
        if (idx < 8)       { tab = rpt + (size_t)(ti - idx + 7) * HD_;          dst = &relT[row][idx]; }
        else if (idx < 22) { tab = rph + (size_t)(hi - (idx - 8) + 13) * HD_;   dst = &relH[row][idx - 8]; }
        else               { tab = rpw + (size_t)(wi - (idx - 22) + 13) * HD_;  dst = &relW[row][idx - 22]; }
        float acc = 0.f;
        if (valid) {
            #pragma unroll 8
            for (int d = 0; d < 64; d++) acc += QT[d][row] * tab[d];
        }
        *dst = acc;
    }

    const int r = tid >> 4;
    const int c = tid & 15;

    float mrow[4], lrow[4], O[4][4];
    #pragma unroll
    for (int i = 0; i < 4; i++) {
        mrow[i] = -1e30f; lrow[i] = 0.f;
        #pragma unroll
        for (int j = 0; j < 4; j++) O[i][j] = 0.f;
    }

    for (int kt = 0; kt < NKT; kt++) {
        __syncthreads();   // prior-tile PV reads done before restaging
        // ---- stage K^T and V ----
        {
            const int row = tid >> 2, mm = tid & 3;
            const int jg = kt * 64 + row;
            float kb[16];
            float4 vb[4];
            if (jg < N_) {
                const float4* ks = reinterpret_cast<const float4*>(Kg + (size_t)jg * HD_ + mm * 16);
                const float4* vs = reinterpret_cast<const float4*>(Vg + (size_t)jg * HD_ + mm * 16);
                *reinterpret_cast<float4*>(&kb[0])  = ks[0];
                *reinterpret_cast<float4*>(&kb[4])  = ks[1];
                *reinterpret_cast<float4*>(&kb[8])  = ks[2];
                *reinterpret_cast<float4*>(&kb[12]) = ks[3];
                vb[0] = vs[0]; vb[1] = vs[1]; vb[2] = vs[2]; vb[3] = vs[3];
            } else {
                #pragma unroll
                for (int ii = 0; ii < 16; ii++) kb[ii] = 0.f;
                #pragma unroll
                for (int ii = 0; ii < 4; ii++) vb[ii] = make_float4(0.f, 0.f, 0.f, 0.f);
            }
            const int d0 = mm * 16;
            #pragma unroll
            for (int ii = 0; ii < 16; ii++) KT[d0 + ii][row] = kb[ii];
            #pragma unroll
            for (int ii = 0; ii < 4; ii++)
                *reinterpret_cast<float4*>(&Vs[row][d0 + 4 * ii]) = vb[ii];
        }
        __syncthreads();

        // ---- S = Q K^T (4x4 per thread) ----
        float S[4][4];
        #pragma unroll
        for (int i = 0; i < 4; i++)
            #pragma unroll
            for (int j = 0; j < 4; j++) S[i][j] = 0.f;

        #pragma unroll 4
        for (int k = 0; k < 64; k++) {
            float4 qv = *reinterpret_cast<const float4*>(&QT[k][r * 4]);
            float4 kv = *reinterpret_cast<const float4*>(&KT[k][c * 4]);
            float qa[4] = {qv.x, qv.y, qv.z, qv.w};
            float kb2[4] = {kv.x, kv.y, kv.z, kv.w};
            #pragma unroll
            for (int i = 0; i < 4; i++)
                #pragma unroll
                for (int j = 0; j < 4; j++) S[i][j] += qa[i] * kb2[j];
        }

        // ---- scale + rel bias + padding mask ----
        int tj[4], hj[4], wj[4];
        bool cvalid[4], cbias[4];
        #pragma unroll
        for (int j = 0; j < 4; j++) {
            int col = kt * 64 + c * 4 + j;
            cvalid[j] = (col < N_);
            cbias[j] = (col >= 1 && col < N_);
            int mj = cbias[j] ? col - 1 : 0;
            tj[j] = mj / 196; int rr3 = mj - tj[j] * 196;
            hj[j] = rr3 / 14; wj[j] = rr3 - hj[j] * 14;
        }
        #pragma unroll
        for (int i = 0; i < 4; i++) {
            int qi = q0 + r * 4 + i;
            bool qb = (qi >= 1 && qi < N_);
            #pragma unroll
            for (int j = 0; j < 4; j++) {
                float s;
                if (!cvalid[j]) s = -1e30f;
                else {
                    s = S[i][j] * 0.125f;
                    if (qb && cbias[j])
                        s += relT[r * 4 + i][tj[j]] + relH[r * 4 + i][hj[j]] + relW[r * 4 + i][wj[j]];
                }
                S[i][j] = s;
            }
        }

        // ---- online softmax update + P to LDS ----
        #pragma unroll
        for (int i = 0; i < 4; i++) {
            float rm = fmaxf(fmaxf(S[i][0], S[i][1]), fmaxf(S[i][2], S[i][3]));
            rm = fmaxf(rm, __shfl_xor(rm, 1));
            rm = fmaxf(rm, __shfl_xor(rm, 2));
            rm = fmaxf(rm, __shfl_xor(rm, 4));
            rm = fmaxf(rm, __shfl_xor(rm, 8));
            float mn = fmaxf(mrow[i], rm);
            float fac = __expf(mrow[i] - mn);
            mrow[i] = mn;
            float ps = 0.f;
            #pragma unroll
            for (int j = 0; j < 4; j++) { float p = __expf(S[i][j] - mn); S[i][j] = p; ps += p; }
            ps += __shfl_xor(ps, 1); ps += __shfl_xor(ps, 2);
            ps += __shfl_xor(ps, 4); ps += __shfl_xor(ps, 8);
            lrow[i] = lrow[i] * fac + ps;
            #pragma unroll
            for (int j = 0; j < 4; j++) O[i][j] *= fac;
            float4 pw = {S[i][0], S[i][1], S[i][2], S[i][3]};
            *reinterpret_cast<float4*>(&Ps[r * 4 + i][c * 4]) = pw;
        }
        __syncthreads();

        // ---- O += P @ V ----
        #pragma unroll 2
        for (int k4 = 0; k4 < 16; k4++) {
            float pr[4][4], vv[4][4];
            #pragma unroll
            for (int i = 0; i < 4; i++) {
                float4 t = *reinterpret_cast<const float4*>(&Ps[r * 4 + i][k4 * 4]);
                pr[i][0] = t.x; pr[i][1] = t.y; pr[i][2] = t.z; pr[i][3] = t.w;
            }
            #pragma unroll
            for (int kk = 0; kk < 4; kk++) {
                float4 t = *reinterpret_cast<const float4*>(&Vs[k4 * 4 + kk][c * 4]);
                vv[kk][0] = t.x; vv[kk][1] = t.y; vv[kk][2] = t.z; vv[kk][3] = t.w;
            }
            #pragma unroll
            for (int i = 0; i < 4; i++)
                #pragma unroll
                for (int kk = 0; kk < 4; kk++)
                    #pragma unroll
                    for (int j = 0; j < 4; j++)
                        O[i][j] += pr[i][kk] * vv[kk][j];
        }
    }

    // ---- finalize: /l, +residual q, store ----
    #pragma unroll
    for (int i = 0; i < 4; i++) {
        int row = r * 4 + i, qi = q0 + row;
        if (qi >= N_) continue;
        float inv = 1.f / lrow[i];
        float4 o;
        float r0 = (qi > 0) ? QT[c * 4 + 0][row] : 0.f;
        float r1 = (qi > 0) ? QT[c * 4 + 1][row] : 0.f;
        float r2 = (qi > 0) ? QT[c * 4 + 2][row] : 0.f;
        float r3 = (qi > 0) ? QT[c * 4 + 3][row] : 0.f;
        o.x = O[i][0] * inv + r0;
        o.y = O[i][1] * inv + r1;
        o.z = O[i][2] * inv + r2;
        o.w = O[i][3] * inv + r3;
        *reinterpret_cast<float4*>(aout + (size_t)(b * N_ + qi) * (HEADS_ * HD_) + h * HD_ + c * 4) = o;
    }
}

extern "C" void kernel_launch(void* const* d_in, const int* in_sizes, int n_in,
                              void* d_out, int out_size, void* d_ws, size_t ws_size,
                              hipStream_t stream) {
    const float* x    = (const float*)d_in[0];
    const float* Wqkv = (const float*)d_in[1];
    const float* bqkv = (const float*)d_in[2];
    const float* kq   = (const float*)d_in[3];
    const float* kk   = (const float*)d_in[4];
    const float* kv   = (const float*)d_in[5];
    const float* nqw  = (const float*)d_in[6];
    const float* nqb  = (const float*)d_in[7];
    const float* nkw  = (const float*)d_in[8];
    const float* nkb  = (const float*)d_in[9];
    const float* nvw  = (const float*)d_in[10];
    const float* nvb  = (const float*)d_in[11];
    const float* rpt  = (const float*)d_in[12];
    const float* rph  = (const float*)d_in[13];
    const float* rpw  = (const float*)d_in[14];
    const float* Wproj= (const float*)d_in[15];
    const float* bproj= (const float*)d_in[16];
    float* out = (float*)d_out;

    const size_t qkv_elems  = (size_t)M_ * QKVD;
    const size_t pool_elems = (size_t)B_ * HEADS_ * N_ * HD_;
    float* qkvp = (float*)d_ws;
    float* pq   = qkvp + qkv_elems;
    float* pk   = pq + pool_elems;
    float* pv   = pk + pool_elems;
    float* aout = qkvp;    // alias: qkv scratch dead after pool_ln

    dim3 g1(QKVD / 128, (M_ + 127) / 128);
    gemm_bias<<<g1, 256, 0, stream>>>(x, Wqkv, bqkv, qkvp, M_, IND, QKVD);

    pool_ln<<<3 * B_ * HEADS_ * N_, 64, 0, stream>>>(qkvp, kq, kk, kv,
        nqw, nqb, nkw, nkb, nvw, nvb, pq, pk, pv);

    attn_flash<<<B_ * HEADS_ * NKT, 256, 0, stream>>>(pq, pk, pv, rpt, rph, rpw, aout);

    dim3 g2((HEADS_ * HD_) / 128, (M_ + 127) / 128);
    gemm_bias<<<g2, 256, 0, stream>>>(aout, Wproj, bproj, out, M_, IND, HEADS_ * HD_);
}

// Round 4
// 1080.767 us; speedup vs baseline: 7.1875x; 1.3160x over previous
//
#include <hip/hip_runtime.h>
#include <hip/hip_bf16.h>

#define B_ 4
#define N_ 1569
#define IND 768
#define HEADS_ 12
#define HD_ 64
#define T0_ 8
#define H0_ 14
#define W0_ 14
#define M_ (B_*N_)          // 6276
#define MPAD 6400           // 50*128
#define QKVD (3*IND)        // 2304
#define NKT 25              // ceil(1569/64)

typedef __attribute__((ext_vector_type(8))) float float8;
typedef __attribute__((ext_vector_type(8))) short short8v;
typedef __attribute__((ext_vector_type(4))) float f32x4;

__device__ __forceinline__ short f2bfs(float f) {
    __hip_bfloat16 h = __float2bfloat16(f);
    return *reinterpret_cast<short*>(&h);
}

// ---------------- f32 -> bf16 row-wise convert with zero row padding ----------------
__global__ __launch_bounds__(256) void f32_to_bf16_rows(
        const float* __restrict__ src, short* __restrict__ dst, int rows, int cols) {
    const int r = blockIdx.x;
    const bool live = r < rows;
    for (int c = threadIdx.x; c < cols; c += 256) {
        float v = live ? src[(size_t)r * cols + c] : 0.f;
        dst[(size_t)r * cols + c] = f2bfs(v);
    }
}

// ---------------- W[K][N] f32 -> WT[N][K] bf16 ----------------
__global__ __launch_bounds__(256) void transpose_f32_bf16(
        const float* __restrict__ W, short* __restrict__ WT, int K, int N) {
    __shared__ float t[32][33];
    const int n0 = blockIdx.x * 32, k0 = blockIdx.y * 32;
    const int tx = threadIdx.x & 31, ty = threadIdx.x >> 5;  // ty in 0..7
    #pragma unroll
    for (int p = 0; p < 4; p++)
        t[ty + 8 * p][tx] = W[(size_t)(k0 + ty + 8 * p) * N + n0 + tx];
    __syncthreads();
    #pragma unroll
    for (int p = 0; p < 4; p++)
        WT[(size_t)(n0 + ty + 8 * p) * K + k0 + tx] = f2bfs(t[tx][ty + 8 * p]);
}

// ---------------- MFMA GEMM: C[M,N] = A[Mpad,K](bf16) * BT[N,K](bf16)^T + bias ----------------
// 128x128 tile, BK=32, 4 waves (2x2), each wave 64x64 via 4x4 mfma_16x16x32 frags.
__global__ __launch_bounds__(256) void gemm_mfma(
        const short* __restrict__ A, const short* __restrict__ BT,
        const float* __restrict__ bias, float* __restrict__ C,
        int M, int N, int K) {
    __shared__ __align__(16) short As[128 * 32];
    __shared__ __align__(16) short Bs[128 * 32];
    const int tid = threadIdx.x;
    const int lane = tid & 63;
    const int wid = tid >> 6;
    const int bm = blockIdx.y * 128;
    const int bn = blockIdx.x * 128;
    const int wr = (wid >> 1) * 64, wc = (wid & 1) * 64;
    const int larow = lane & 15, lak = (lane >> 4) * 8;
    const int srow = tid >> 2, sk = (tid & 3) * 8;   // staging: 64 rows x 32k per pass

    f32x4 acc[4][4];
    #pragma unroll
    for (int m = 0; m < 4; m++)
        #pragma unroll
        for (int n = 0; n < 4; n++) acc[m][n] = (f32x4){0.f, 0.f, 0.f, 0.f};

    for (int kt = 0; kt < K; kt += 32) {
        short8v a0 = *(const short8v*)(A + (size_t)(bm + srow) * K + kt + sk);
        short8v a1 = *(const short8v*)(A + (size_t)(bm + 64 + srow) * K + kt + sk);
        short8v b0 = *(const short8v*)(BT + (size_t)(bn + srow) * K + kt + sk);
        short8v b1 = *(const short8v*)(BT + (size_t)(bn + 64 + srow) * K + kt + sk);
        __syncthreads();   // previous tile's fragment reads complete
        *(short8v*)&As[srow * 32 + sk] = a0;
        *(short8v*)&As[(64 + srow) * 32 + sk] = a1;
        *(short8v*)&Bs[srow * 32 + sk] = b0;
        *(short8v*)&Bs[(64 + srow) * 32 + sk] = b1;
        __syncthreads();

        short8v af[4], bfv[4];
        #pragma unroll
        for (int m = 0; m < 4; m++)
            af[m] = *(const short8v*)&As[(wr + m * 16 + larow) * 32 + lak];
        #pragma unroll
        for (int n = 0; n < 4; n++)
            bfv[n] = *(const short8v*)&Bs[(wc + n * 16 + larow) * 32 + lak];
        #pragma unroll
        for (int m = 0; m < 4; m++)
            #pragma unroll
            for (int n = 0; n < 4; n++)
                acc[m][n] = __builtin_amdgcn_mfma_f32_16x16x32_bf16(af[m], bfv[n], acc[m][n], 0, 0, 0);
    }

    // epilogue: C/D layout col=lane&15, row=(lane>>4)*4+reg
    const int crow = (lane >> 4) * 4;
    const int ccol = lane & 15;
    #pragma unroll
    for (int n = 0; n < 4; n++) {
        const int col = bn + wc + n * 16 + ccol;
        const float bv = bias[col];
        #pragma unroll
        for (int m = 0; m < 4; m++) {
            #pragma unroll
            for (int r2 = 0; r2 < 4; r2++) {
                const int row = bm + wr + m * 16 + crow + r2;
                if (row < M) C[(size_t)row * N + col] = acc[m][n][r2] + bv;
            }
        }
    }
}

// ---------------- depthwise 3x3x3 conv pool + LayerNorm(64) ----------------
__global__ __launch_bounds__(64) void pool_ln(
        const float* __restrict__ qkv,
        const float* __restrict__ kq, const float* __restrict__ kk,
        const float* __restrict__ kv,
        const float* __restrict__ nqw, const float* __restrict__ nqb,
        const float* __restrict__ nkw, const float* __restrict__ nkb,
        const float* __restrict__ nvw, const float* __restrict__ nvb,
        float* __restrict__ pq, float* __restrict__ pk, float* __restrict__ pv) {
    const int d = threadIdx.x;
    int bid = blockIdx.x;
    const int n = bid % N_; bid /= N_;
    const int head = bid % HEADS_; bid /= HEADS_;
    const int b = bid % B_;
    const int s = bid / B_;

    const float* kern = (s == 0) ? kq : ((s == 1) ? kk : kv);
    const float* lw = (s == 0) ? nqw : ((s == 1) ? nkw : nvw);
    const float* lb = (s == 0) ? nqb : ((s == 1) ? nkb : nvb);
    float* dst = (s == 0) ? pq : ((s == 1) ? pk : pv);

    const size_t colbase = (size_t)s * IND + head * HD_ + d;
    float y;
    if (n == 0) {
        y = qkv[(size_t)(b * N_) * QKVD + colbase];
    } else {
        const int m = n - 1;
        const int ti = m / (H0_ * W0_);
        const int rr = m % (H0_ * W0_);
        const int hi = rr / W0_, wi = rr % W0_;
        float acc = 0.f;
        #pragma unroll
        for (int kt = 0; kt < 3; kt++) {
            int t2 = ti + kt - 1;
            if (t2 < 0 || t2 >= T0_) continue;
            #pragma unroll
            for (int kh = 0; kh < 3; kh++) {
                int h2 = hi + kh - 1;
                if (h2 < 0 || h2 >= H0_) continue;
                #pragma unroll
                for (int kw = 0; kw < 3; kw++) {
                    int w2 = wi + kw - 1;
                    if (w2 < 0 || w2 >= W0_) continue;
                    int node = 1 + (t2 * H0_ + h2) * W0_ + w2;
                    float xv = qkv[(size_t)(b * N_ + node) * QKVD + colbase];
                    float kvv = kern[d * 27 + (kt * 3 + kh) * 3 + kw];
                    acc += xv * kvv;
                }
            }
        }
        y = acc;
    }
    float s1 = y;
    #pragma unroll
    for (int o = 32; o > 0; o >>= 1) s1 += __shfl_xor(s1, o);
    float mu = s1 * (1.f / 64.f);
    float diff = y - mu;
    float s2 = diff * diff;
    #pragma unroll
    for (int o = 32; o > 0; o >>= 1) s2 += __shfl_xor(s2, o);
    float var = s2 * (1.f / 64.f);
    float out = diff * rsqrtf(var + 1e-5f) * lw[d] + lb[d];
    dst[((size_t)((b * HEADS_ + head) * N_) + n) * HD_ + d] = out;
}

// ---------------- flash attention: 64-query tile per block (f32 vector) ----------------
__global__ __launch_bounds__(256) void attn_flash(
        const float* __restrict__ pq, const float* __restrict__ pk, const float* __restrict__ pv,
        const float* __restrict__ rpt, const float* __restrict__ rph,
        const float* __restrict__ rpw, float* __restrict__ aout) {
    __shared__ __align__(16) float QT[64][68];   // [d][qrow]
    __shared__ __align__(16) float KT[64][68];   // [d][kcol]
    __shared__ __align__(16) float Vs[64][68];   // [krow][d]
    __shared__ __align__(16) float Ps[64][68];   // [qrow][kcol]
    __shared__ float relT[64][8];
    __shared__ float relH[64][14];
    __shared__ float relW[64][14];

    const int tid = threadIdx.x;
    int bid = blockIdx.x;
    const int qt = bid % NKT; bid /= NKT;
    const int h = bid % HEADS_;
    const int b = bid / HEADS_;
    const int q0 = qt * 64;

    const size_t bh = (size_t)((b * HEADS_ + h) * N_) * HD_;
    const float* Qg = pq + bh;
    const float* Kg = pk + bh;
    const float* Vg = pv + bh;

    {
        const int row = tid >> 2, mm = tid & 3;
        const int qi = q0 + row;
        float buf[16];
        if (qi < N_) {
            const float4* s = reinterpret_cast<const float4*>(Qg + (size_t)qi * HD_ + mm * 16);
            *reinterpret_cast<float4*>(&buf[0])  = s[0];
            *reinterpret_cast<float4*>(&buf[4])  = s[1];
            *reinterpret_cast<float4*>(&buf[8])  = s[2];
            *reinterpret_cast<float4*>(&buf[12]) = s[3];
        } else {
            #pragma unroll
            for (int ii = 0; ii < 16; ii++) buf[ii] = 0.f;
        }
        const int d0 = mm * 16;
        #pragma unroll
        for (int ii = 0; ii < 16; ii++) QT[d0 + ii][row] = buf[ii];
    }
    __syncthreads();

    #pragma unroll
    for (int it = 0; it < 9; it++) {
        int flat = it * 256 + tid;
        int row = flat / 36, idx = flat - row * 36;
        int qi = q0 + row;
        bool valid = (qi >= 1 && qi < N_);
        int m = valid ? (qi - 1) : 0;
        int ti = m / 196, rr2 = m - ti * 196;
        int hi = rr2 / 14, wi = rr2 - hi * 14;
        const float* tab;
        float* dst;
        if (idx < 8)       { tab = rpt + (size_t)(ti - idx + 7) * HD_;          dst = &relT[row][idx]; }
        else if (idx < 22) { tab = rph + (size_t)(hi - (idx - 8) + 13) * HD_;   dst = &relH[row][idx - 8]; }
        else               { tab = rpw + (size_t)(wi - (idx - 22) + 13) * HD_;  dst = &relW[row][idx - 22]; }
        float acc = 0.f;
        if (valid) {
            #pragma unroll 8
            for (int d = 0; d < 64; d++) acc += QT[d][row] * tab[d];
        }
        *dst = acc;
    }

    const int r = tid >> 4;
    const int c = tid & 15;

    float mrow[4], lrow[4], O[4][4];
    #pragma unroll
    for (int i = 0; i < 4; i++) {
        mrow[i] = -1e30f; lrow[i] = 0.f;
        #pragma unroll
        for (int j = 0; j < 4; j++) O[i][j] = 0.f;
    }

    for (int kt = 0; kt < NKT; kt++) {
        __syncthreads();
        {
            const int row = tid >> 2, mm = tid & 3;
            const int jg = kt * 64 + row;
            float kb[16];
            float4 vb[4];
            if (jg < N_) {
                const float4* ks = reinterpret_cast<const float4*>(Kg + (size_t)jg * HD_ + mm * 16);
                const float4* vs = reinterpret_cast<const float4*>(Vg + (size_t)jg * HD_ + mm * 16);
                *reinterpret_cast<float4*>(&kb[0])  = ks[0];
                *reinterpret_cast<float4*>(&kb[4])  = ks[1];
                *reinterpret_cast<float4*>(&kb[8])  = ks[2];
                *reinterpret_cast<float4*>(&kb[12]) = ks[3];
                vb[0] = vs[0]; vb[1] = vs[1]; vb[2] = vs[2]; vb[3] = vs[3];
            } else {
                #pragma unroll
                for (int ii = 0; ii < 16; ii++) kb[ii] = 0.f;
                #pragma unroll
                for (int ii = 0; ii < 4; ii++) vb[ii] = make_float4(0.f, 0.f, 0.f, 0.f);
            }
            const int d0 = mm * 16;
            #pragma unroll
            for (int ii = 0; ii < 16; ii++) KT[d0 + ii][row] = kb[ii];
            #pragma unroll
            for (int ii = 0; ii < 4; ii++)
                *reinterpret_cast<float4*>(&Vs[row][d0 + 4 * ii]) = vb[ii];
        }
        __syncthreads();

        float S[4][4];
        #pragma unroll
        for (int i = 0; i < 4; i++)
            #pragma unroll
            for (int j = 0; j < 4; j++) S[i][j] = 0.f;

        #pragma unroll 4
        for (int k = 0; k < 64; k++) {
            float4 qv = *reinterpret_cast<const float4*>(&QT[k][r * 4]);
            float4 kv = *reinterpret_cast<const float4*>(&KT[k][c * 4]);
            float qa[4] = {qv.x, qv.y, qv.z, qv.w};
            float kb2[4] = {kv.x, kv.y, kv.z, kv.w};
            #pragma unroll
            for (int i = 0; i < 4; i++)
                #pragma unroll
                for (int j = 0; j < 4; j++) S[i][j] += qa[i] * kb2[j];
        }

        int tj[4], hj[4], wj[4];
        bool cvalid[4], cbias[4];
        #pragma unroll
        for (int j = 0; j < 4; j++) {
            int col = kt * 64 + c * 4 + j;
            cvalid[j] = (col < N_);
            cbias[j] = (col >= 1 && col < N_);
            int mj = cbias[j] ? col - 1 : 0;
            tj[j] = mj / 196; int rr3 = mj - tj[j] * 196;
            hj[j] = rr3 / 14; wj[j] = rr3 - hj[j] * 14;
        }
        #pragma unroll
        for (int i = 0; i < 4; i++) {
            int qi = q0 + r * 4 + i;
            bool qb = (qi >= 1 && qi < N_);
            #pragma unroll
            for (int j = 0; j < 4; j++) {
                float s;
                if (!cvalid[j]) s = -1e30f;
                else {
                    s = S[i][j] * 0.125f;
                    if (qb && cbias[j])
                        s += relT[r * 4 + i][tj[j]] + relH[r * 4 + i][hj[j]] + relW[r * 4 + i][wj[j]];
                }
                S[i][j] = s;
            }
        }

        #pragma unroll
        for (int i = 0; i < 4; i++) {
            float rm = fmaxf(fmaxf(S[i][0], S[i][1]), fmaxf(S[i][2], S[i][3]));
            rm = fmaxf(rm, __shfl_xor(rm, 1));
            rm = fmaxf(rm, __shfl_xor(rm, 2));
            rm = fmaxf(rm, __shfl_xor(rm, 4));
            rm = fmaxf(rm, __shfl_xor(rm, 8));
            float mn = fmaxf(mrow[i], rm);
            float fac = __expf(mrow[i] - mn);
            mrow[i] = mn;
            float ps = 0.f;
            #pragma unroll
            for (int j = 0; j < 4; j++) { float p = __expf(S[i][j] - mn); S[i][j] = p; ps += p; }
            ps += __shfl_xor(ps, 1); ps += __shfl_xor(ps, 2);
            ps += __shfl_xor(ps, 4); ps += __shfl_xor(ps, 8);
            lrow[i] = lrow[i] * fac + ps;
            #pragma unroll
            for (int j = 0; j < 4; j++) O[i][j] *= fac;
            float4 pw = {S[i][0], S[i][1], S[i][2], S[i][3]};
            *reinterpret_cast<float4*>(&Ps[r * 4 + i][c * 4]) = pw;
        }
        __syncthreads();

        #pragma unroll 2
        for (int k4 = 0; k4 < 16; k4++) {
            float pr[4][4], vv[4][4];
            #pragma unroll
            for (int i = 0; i < 4; i++) {
                float4 t = *reinterpret_cast<const float4*>(&Ps[r * 4 + i][k4 * 4]);
                pr[i][0] = t.x; pr[i][1] = t.y; pr[i][2] = t.z; pr[i][3] = t.w;
            }
            #pragma unroll
            for (int kk = 0; kk < 4; kk++) {
                float4 t = *reinterpret_cast<const float4*>(&Vs[k4 * 4 + kk][c * 4]);
                vv[kk][0] = t.x; vv[kk][1] = t.y; vv[kk][2] = t.z; vv[kk][3] = t.w;
            }
            #pragma unroll
            for (int i = 0; i < 4; i++)
                #pragma unroll
                for (int kk = 0; kk < 4; kk++)
                    #pragma unroll
                    for (int j = 0; j < 4; j++)
                        O[i][j] += pr[i][kk] * vv[kk][j];
        }
    }

    #pragma unroll
    for (int i = 0; i < 4; i++) {
        int row = r * 4 + i, qi = q0 + row;
        if (qi >= N_) continue;
        float inv = 1.f / lrow[i];
        float4 o;
        float r0 = (qi > 0) ? QT[c * 4 + 0][row] : 0.f;
        float r1 = (qi > 0) ? QT[c * 4 + 1][row] : 0.f;
        float r2 = (qi > 0) ? QT[c * 4 + 2][row] : 0.f;
        float r3 = (qi > 0) ? QT[c * 4 + 3][row] : 0.f;
        o.x = O[i][0] * inv + r0;
        o.y = O[i][1] * inv + r1;
        o.z = O[i][2] * inv + r2;
        o.w = O[i][3] * inv + r3;
        *reinterpret_cast<float4*>(aout + (size_t)(b * N_ + qi) * (HEADS_ * HD_) + h * HD_ + c * 4) = o;
    }
}

extern "C" void kernel_launch(void* const* d_in, const int* in_sizes, int n_in,
                              void* d_out, int out_size, void* d_ws, size_t ws_size,
                              hipStream_t stream) {
    const float* x    = (const float*)d_in[0];
    const float* Wqkv = (const float*)d_in[1];
    const float* bqkv = (const float*)d_in[2];
    const float* kq   = (const float*)d_in[3];
    const float* kk   = (const float*)d_in[4];
    const float* kv   = (const float*)d_in[5];
    const float* nqw  = (const float*)d_in[6];
    const float* nqb  = (const float*)d_in[7];
    const float* nkw  = (const float*)d_in[8];
    const float* nkb  = (const float*)d_in[9];
    const float* nvw  = (const float*)d_in[10];
    const float* nvb  = (const float*)d_in[11];
    const float* rpt  = (const float*)d_in[12];
    const float* rph  = (const float*)d_in[13];
    const float* rpw  = (const float*)d_in[14];
    const float* Wproj= (const float*)d_in[15];
    const float* bproj= (const float*)d_in[16];
    float* out = (float*)d_out;

    const size_t qkv_elems  = (size_t)M_ * QKVD;                  // 14,459,904 f32
    const size_t pool_elems = (size_t)B_ * HEADS_ * N_ * HD_;     //  4,819,968 f32
    float* qkvp = (float*)d_ws;
    float* pq   = qkvp + qkv_elems;
    float* pk   = pq + pool_elems;
    float* pv   = pk + pool_elems;
    float* aout = qkvp;                       // alias: qkv scratch dead after pool_ln
    short* xbf  = (short*)(pv + pool_elems);  // [6400][768] bf16; reused as aoutbf
    short* w1t  = xbf + (size_t)MPAD * IND;   // [2304][768] bf16; reused as w2t
                                              // total ws ≈ 129 MB

    // GEMM1: qkv = x @ Wqkv + b  (bf16 MFMA)
    f32_to_bf16_rows<<<MPAD, 256, 0, stream>>>(x, xbf, M_, IND);
    transpose_f32_bf16<<<dim3(QKVD / 32, IND / 32), 256, 0, stream>>>(Wqkv, w1t, IND, QKVD);
    gemm_mfma<<<dim3(QKVD / 128, MPAD / 128), 256, 0, stream>>>(xbf, w1t, bqkv, qkvp, M_, QKVD, IND);

    pool_ln<<<3 * B_ * HEADS_ * N_, 64, 0, stream>>>(qkvp, kq, kk, kv,
        nqw, nqb, nkw, nkb, nvw, nvb, pq, pk, pv);

    attn_flash<<<B_ * HEADS_ * NKT, 256, 0, stream>>>(pq, pk, pv, rpt, rph, rpw, aout);

    // GEMM2: out = aout @ Wproj + b  (bf16 MFMA)
    f32_to_bf16_rows<<<MPAD, 256, 0, stream>>>(aout, xbf, M_, IND);
    transpose_f32_bf16<<<dim3(IND / 32, IND / 32), 256, 0, stream>>>(Wproj, w1t, IND, IND);
    gemm_mfma<<<dim3(IND / 128, MPAD / 128), 256, 0, stream>>>(xbf, w1t, bproj, out, M_, IND, IND);
}

// Round 5
// 754.061 us; speedup vs baseline: 10.3016x; 1.4333x over previous
//
#include <hip/hip_runtime.h>
#include <hip/hip_bf16.h>

#define B_ 4
#define N_ 1569
#define IND 768
#define HEADS_ 12
#define HD_ 64
#define T0_ 8
#define H0_ 14
#define W0_ 14
#define M_ (B_*N_)          // 6276
#define MPAD 6400           // 50*128
#define QKVD (3*IND)        // 2304
#define NKT 25              // ceil(1569/64)

typedef __attribute__((ext_vector_type(8))) short short8v;
typedef __attribute__((ext_vector_type(4))) float f32x4;

__device__ __forceinline__ short f2bfs(float f) {
    __hip_bfloat16 h = __float2bfloat16(f);
    return *reinterpret_cast<short*>(&h);
}

// ---- swizzled LDS helpers for [64 rows][64 bf16] tiles (128B rows) ----
// T2: byte ^= (row&7)<<4  — 16B-block XOR within 8-row stripes.
__device__ __forceinline__ short8v lds_read8(const short* base, int row, int byteInRow) {
    int byte = row * 128 + (byteInRow ^ ((row & 7) << 4));
    return *reinterpret_cast<const short8v*>(reinterpret_cast<const char*>(base) + byte);
}
__device__ __forceinline__ void lds_write8(short* base, int row, int byteInRow, short8v v) {
    int byte = row * 128 + (byteInRow ^ ((row & 7) << 4));
    *reinterpret_cast<short8v*>(reinterpret_cast<char*>(base) + byte) = v;
}
__device__ __forceinline__ void lds_write1(short* base, int row, int col, short v) {
    int byte = row * 128 + ((col * 2) ^ ((row & 7) << 4));
    *reinterpret_cast<short*>(reinterpret_cast<char*>(base) + byte) = v;
}

// ---------------- f32 -> bf16 row-wise convert with zero row padding ----------------
__global__ __launch_bounds__(256) void f32_to_bf16_rows(
        const float* __restrict__ src, short* __restrict__ dst, int rows, int cols) {
    const int r = blockIdx.x;
    const bool live = r < rows;
    for (int c = threadIdx.x; c < cols; c += 256) {
        float v = live ? src[(size_t)r * cols + c] : 0.f;
        dst[(size_t)r * cols + c] = f2bfs(v);
    }
}

// ---------------- W[K][N] f32 -> WT[N][K] bf16 ----------------
__global__ __launch_bounds__(256) void transpose_f32_bf16(
        const float* __restrict__ W, short* __restrict__ WT, int K, int N) {
    __shared__ float t[32][33];
    const int n0 = blockIdx.x * 32, k0 = blockIdx.y * 32;
    const int tx = threadIdx.x & 31, ty = threadIdx.x >> 5;
    #pragma unroll
    for (int p = 0; p < 4; p++)
        t[ty + 8 * p][tx] = W[(size_t)(k0 + ty + 8 * p) * N + n0 + tx];
    __syncthreads();
    #pragma unroll
    for (int p = 0; p < 4; p++)
        WT[(size_t)(n0 + ty + 8 * p) * K + k0 + tx] = f2bfs(t[tx][ty + 8 * p]);
}

// ---------------- MFMA GEMM: C[M,N] = A[Mpad,K](bf16) * BT[N,K](bf16)^T + bias ----------------
__global__ __launch_bounds__(256) void gemm_mfma(
        const short* __restrict__ A, const short* __restrict__ BT,
        const float* __restrict__ bias, float* __restrict__ C,
        int M, int N, int K) {
    __shared__ __align__(16) short As[128 * 32];
    __shared__ __align__(16) short Bs[128 * 32];
    const int tid = threadIdx.x;
    const int lane = tid & 63;
    const int wid = tid >> 6;
    const int bm = blockIdx.y * 128;
    const int bn = blockIdx.x * 128;
    const int wr = (wid >> 1) * 64, wc = (wid & 1) * 64;
    const int larow = lane & 15, lak = (lane >> 4) * 8;
    const int srow = tid >> 2, sk = (tid & 3) * 8;

    f32x4 acc[4][4];
    #pragma unroll
    for (int m = 0; m < 4; m++)
        #pragma unroll
        for (int n = 0; n < 4; n++) acc[m][n] = (f32x4){0.f, 0.f, 0.f, 0.f};

    for (int kt = 0; kt < K; kt += 32) {
        short8v a0 = *(const short8v*)(A + (size_t)(bm + srow) * K + kt + sk);
        short8v a1 = *(const short8v*)(A + (size_t)(bm + 64 + srow) * K + kt + sk);
        short8v b0 = *(const short8v*)(BT + (size_t)(bn + srow) * K + kt + sk);
        short8v b1 = *(const short8v*)(BT + (size_t)(bn + 64 + srow) * K + kt + sk);
        __syncthreads();
        *(short8v*)&As[srow * 32 + sk] = a0;
        *(short8v*)&As[(64 + srow) * 32 + sk] = a1;
        *(short8v*)&Bs[srow * 32 + sk] = b0;
        *(short8v*)&Bs[(64 + srow) * 32 + sk] = b1;
        __syncthreads();

        short8v af[4], bfv[4];
        #pragma unroll
        for (int m = 0; m < 4; m++)
            af[m] = *(const short8v*)&As[(wr + m * 16 + larow) * 32 + lak];
        #pragma unroll
        for (int n = 0; n < 4; n++)
            bfv[n] = *(const short8v*)&Bs[(wc + n * 16 + larow) * 32 + lak];
        #pragma unroll
        for (int m = 0; m < 4; m++)
            #pragma unroll
            for (int n = 0; n < 4; n++)
                acc[m][n] = __builtin_amdgcn_mfma_f32_16x16x32_bf16(af[m], bfv[n], acc[m][n], 0, 0, 0);
    }

    const int crow = (lane >> 4) * 4;
    const int ccol = lane & 15;
    #pragma unroll
    for (int n = 0; n < 4; n++) {
        const int col = bn + wc + n * 16 + ccol;
        const float bv = bias[col];
        #pragma unroll
        for (int m = 0; m < 4; m++) {
            #pragma unroll
            for (int r2 = 0; r2 < 4; r2++) {
                const int row = bm + wr + m * 16 + crow + r2;
                if (row < M) C[(size_t)row * N + col] = acc[m][n][r2] + bv;
            }
        }
    }
}

// ---------------- depthwise 3x3x3 conv pool + LayerNorm(64) ----------------
// outputs: pqf (f32, q only, for residual/rel-tables) + bf16 q/k/v for MFMA attn
__global__ __launch_bounds__(64) void pool_ln(
        const float* __restrict__ qkv,
        const float* __restrict__ kq, const float* __restrict__ kk,
        const float* __restrict__ kv,
        const float* __restrict__ nqw, const float* __restrict__ nqb,
        const float* __restrict__ nkw, const float* __restrict__ nkb,
        const float* __restrict__ nvw, const float* __restrict__ nvb,
        float* __restrict__ pqf, short* __restrict__ qbb,
        short* __restrict__ kbb, short* __restrict__ vbb) {
    const int d = threadIdx.x;
    int bid = blockIdx.x;
    const int n = bid % N_; bid /= N_;
    const int head = bid % HEADS_; bid /= HEADS_;
    const int b = bid % B_;
    const int s = bid / B_;

    const float* kern = (s == 0) ? kq : ((s == 1) ? kk : kv);
    const float* lw = (s == 0) ? nqw : ((s == 1) ? nkw : nvw);
    const float* lb = (s == 0) ? nqb : ((s == 1) ? nkb : nvb);
    short* bdst = (s == 0) ? qbb : ((s == 1) ? kbb : vbb);

    const size_t colbase = (size_t)s * IND + head * HD_ + d;
    float y;
    if (n == 0) {
        y = qkv[(size_t)(b * N_) * QKVD + colbase];
    } else {
        const int m = n - 1;
        const int ti = m / (H0_ * W0_);
        const int rr = m % (H0_ * W0_);
        const int hi = rr / W0_, wi = rr % W0_;
        float acc = 0.f;
        #pragma unroll
        for (int kt = 0; kt < 3; kt++) {
            int t2 = ti + kt - 1;
            if (t2 < 0 || t2 >= T0_) continue;
            #pragma unroll
            for (int kh = 0; kh < 3; kh++) {
                int h2 = hi + kh - 1;
                if (h2 < 0 || h2 >= H0_) continue;
                #pragma unroll
                for (int kw = 0; kw < 3; kw++) {
                    int w2 = wi + kw - 1;
                    if (w2 < 0 || w2 >= W0_) continue;
                    int node = 1 + (t2 * H0_ + h2) * W0_ + w2;
                    float xv = qkv[(size_t)(b * N_ + node) * QKVD + colbase];
                    float kvv = kern[d * 27 + (kt * 3 + kh) * 3 + kw];
                    acc += xv * kvv;
                }
            }
        }
        y = acc;
    }
    float s1 = y;
    #pragma unroll
    for (int o = 32; o > 0; o >>= 1) s1 += __shfl_xor(s1, o);
    float mu = s1 * (1.f / 64.f);
    float diff = y - mu;
    float s2 = diff * diff;
    #pragma unroll
    for (int o = 32; o > 0; o >>= 1) s2 += __shfl_xor(s2, o);
    float var = s2 * (1.f / 64.f);
    float out = diff * rsqrtf(var + 1e-5f) * lw[d] + lb[d];
    const size_t idx = ((size_t)((b * HEADS_ + head) * N_) + n) * HD_ + d;
    bdst[idx] = f2bfs(out);
    if (s == 0) pqf[idx] = out;
}

// ---------------- MFMA flash attention: 64-query tile, 4 waves, bf16 MFMA ----------------
// Writes output directly as bf16 into the GEMM2 A-buffer [MPAD][768].
__global__ __launch_bounds__(256) void attn_mfma(
        const short* __restrict__ qb, const short* __restrict__ kb,
        const short* __restrict__ vb, const float* __restrict__ pqf,
        const float* __restrict__ rpt, const float* __restrict__ rph,
        const float* __restrict__ rpw, short* __restrict__ aoutbf) {
    __shared__ __align__(16) short Qs[64 * 64];   // [q][d] swizzled
    __shared__ __align__(16) short Ks[64 * 64];   // [key][d] swizzled
    __shared__ __align__(16) short VT[64 * 64];   // [d][key] swizzled
    __shared__ __align__(16) short Ps[64 * 64];   // [q][key] swizzled
    __shared__ float relT[64][8];
    __shared__ float relH[64][14];
    __shared__ float relW[64][14];

    const int tid = threadIdx.x;
    const int lane = tid & 63;
    const int wid = tid >> 6;           // wave owns q rows wid*16..+15
    const int larow = lane & 15;
    const int lgrp = lane >> 4;

    int bid = blockIdx.x;
    const int qt = bid % NKT; bid /= NKT;
    const int h = bid % HEADS_;
    const int b = bid / HEADS_;
    const int q0 = qt * 64;
    const size_t base = (size_t)((b * HEADS_ + h) * N_) * HD_;

    // ---- stage Q tile (zero-padded) ----
    {
        const int row = tid >> 2, seg = tid & 3;
        const int qi = q0 + row;
        short8v v0 = {0,0,0,0,0,0,0,0}, v1 = v0;
        if (qi < N_) {
            const short8v* g = (const short8v*)(qb + base + (size_t)qi * HD_ + seg * 16);
            v0 = g[0]; v1 = g[1];
        }
        lds_write8(Qs, row, seg * 32, v0);
        lds_write8(Qs, row, seg * 32 + 16, v1);
    }

    // ---- rel-pos dot tables from f32 q ----
    #pragma unroll
    for (int it = 0; it < 9; it++) {           // 9*256 = 2304 = 64*36
        int flat = it * 256 + tid;
        int row = flat / 36, idx = flat - row * 36;
        int qi = q0 + row;
        bool valid = (qi >= 1 && qi < N_);
        int m = valid ? (qi - 1) : 0;
        int ti = m / 196, rr2 = m - ti * 196;
        int hi = rr2 / 14, wi = rr2 - hi * 14;
        const float* tab;
        float* dst;
        if (idx < 8)       { tab = rpt + (size_t)(ti - idx + 7) * HD_;          dst = &relT[row][idx]; }
        else if (idx < 22) { tab = rph + (size_t)(hi - (idx - 8) + 13) * HD_;   dst = &relH[row][idx - 8]; }
        else               { tab = rpw + (size_t)(wi - (idx - 22) + 13) * HD_;  dst = &relW[row][idx - 22]; }
        float acc = 0.f;
        if (valid) {
            const float4* qp = (const float4*)(pqf + base + (size_t)qi * HD_);
            const float4* tp = (const float4*)tab;
            #pragma unroll 4
            for (int dd = 0; dd < 16; dd++) {
                float4 a = qp[dd], t = tp[dd];
                acc += a.x * t.x + a.y * t.y + a.z * t.z + a.w * t.w;
            }
        }
        *dst = acc;
    }
    __syncthreads();

    // ---- hoist Q A-frags (constant across key tiles) ----
    short8v aq[2];
    #pragma unroll
    for (int ks = 0; ks < 2; ks++)
        aq[ks] = lds_read8(Qs, wid * 16 + larow, ks * 64 + lgrp * 16);

    float mreg[4], lreg[4];
    f32x4 O4[4];
    #pragma unroll
    for (int r = 0; r < 4; r++) { mreg[r] = -1e30f; lreg[r] = 0.f; }
    #pragma unroll
    for (int nf = 0; nf < 4; nf++) O4[nf] = (f32x4){0.f, 0.f, 0.f, 0.f};

    for (int kt = 0; kt < NKT; kt++) {
        __syncthreads();   // prior PV reads of Ks/VT done
        // ---- stage K tile ----
        {
            const int row = tid >> 2, seg = tid & 3;
            const int jg = kt * 64 + row;
            short8v v0 = {0,0,0,0,0,0,0,0}, v1 = v0;
            if (jg < N_) {
                const short8v* g = (const short8v*)(kb + base + (size_t)jg * HD_ + seg * 16);
                v0 = g[0]; v1 = g[1];
            }
            lds_write8(Ks, row, seg * 32, v0);
            lds_write8(Ks, row, seg * 32 + 16, v1);
        }
        // ---- stage V^T tile ----
        {
            const int d = tid & 63, kseg = tid >> 6;
            short tmp[16];
            #pragma unroll
            for (int jj = 0; jj < 16; jj++) {
                int kg = kt * 64 + kseg * 16 + jj;
                tmp[jj] = (kg < N_) ? vb[base + (size_t)kg * HD_ + d] : (short)0;
            }
            lds_write8(VT, d, kseg * 32, *(short8v*)&tmp[0]);
            lds_write8(VT, d, kseg * 32 + 16, *(short8v*)&tmp[8]);
        }
        __syncthreads();

        // ---- S = Q K^T via MFMA ----
        f32x4 s4[4];
        #pragma unroll
        for (int nf = 0; nf < 4; nf++) {
            f32x4 acc = (f32x4){0.f, 0.f, 0.f, 0.f};
            #pragma unroll
            for (int ks = 0; ks < 2; ks++) {
                short8v bk = lds_read8(Ks, nf * 16 + larow, ks * 64 + lgrp * 16);
                acc = __builtin_amdgcn_mfma_f32_16x16x32_bf16(aq[ks], bk, acc, 0, 0, 0);
            }
            s4[nf] = acc;
        }

        // ---- per-column rel-pos indices ----
        bool cvalid[4], cb[4];
        int tj[4], hj[4], wj[4];
        #pragma unroll
        for (int nf = 0; nf < 4; nf++) {
            int col = kt * 64 + nf * 16 + larow;
            cvalid[nf] = (col < N_);
            cb[nf] = (col >= 1 && col < N_);
            int mj = cb[nf] ? col - 1 : 0;
            tj[nf] = mj / 196; int rr3 = mj - tj[nf] * 196;
            hj[nf] = rr3 / 14; wj[nf] = rr3 - hj[nf] * 14;
        }

        // ---- online softmax on C/D layout (row = lgrp*4+r, col = nf*16+larow) ----
        float fac[4];
        #pragma unroll
        for (int r = 0; r < 4; r++) {
            const int rowL = wid * 16 + lgrp * 4 + r;
            const int qi = q0 + rowL;
            const bool qv = (qi >= 1 && qi < N_);
            float sv[4];
            #pragma unroll
            for (int nf = 0; nf < 4; nf++) {
                float x = s4[nf][r] * 0.125f;
                if (qv && cb[nf])
                    x += relT[rowL][tj[nf]] + relH[rowL][hj[nf]] + relW[rowL][wj[nf]];
                sv[nf] = cvalid[nf] ? x : -1e30f;
            }
            float rm = fmaxf(fmaxf(sv[0], sv[1]), fmaxf(sv[2], sv[3]));
            rm = fmaxf(rm, __shfl_xor(rm, 1));
            rm = fmaxf(rm, __shfl_xor(rm, 2));
            rm = fmaxf(rm, __shfl_xor(rm, 4));
            rm = fmaxf(rm, __shfl_xor(rm, 8));
            float mn = fmaxf(mreg[r], rm);
            float f = __expf(mreg[r] - mn);
            mreg[r] = mn;
            float ps = 0.f;
            #pragma unroll
            for (int nf = 0; nf < 4; nf++) {
                float p = __expf(sv[nf] - mn);
                ps += p;
                lds_write1(Ps, rowL, nf * 16 + larow, f2bfs(p));
            }
            ps += __shfl_xor(ps, 1); ps += __shfl_xor(ps, 2);
            ps += __shfl_xor(ps, 4); ps += __shfl_xor(ps, 8);
            lreg[r] = lreg[r] * f + ps;
            fac[r] = f;
        }
        #pragma unroll
        for (int nf = 0; nf < 4; nf++)
            #pragma unroll
            for (int r = 0; r < 4; r++) O4[nf][r] *= fac[r];
        __syncthreads();   // Ps visible (and ordered vs next restage)

        // ---- O += P V via MFMA ----
        short8v ap[2];
        #pragma unroll
        for (int ks = 0; ks < 2; ks++)
            ap[ks] = lds_read8(Ps, wid * 16 + larow, ks * 64 + lgrp * 16);
        #pragma unroll
        for (int nf = 0; nf < 4; nf++) {
            #pragma unroll
            for (int ks = 0; ks < 2; ks++) {
                short8v bv2 = lds_read8(VT, nf * 16 + larow, ks * 64 + lgrp * 16);
                O4[nf] = __builtin_amdgcn_mfma_f32_16x16x32_bf16(ap[ks], bv2, O4[nf], 0, 0, 0);
            }
        }
    }

    // ---- finalize: /l, +residual (f32 q), store bf16 into GEMM2 A-buffer ----
    #pragma unroll
    for (int nf = 0; nf < 4; nf++) {
        const int d = nf * 16 + larow;
        #pragma unroll
        for (int r = 0; r < 4; r++) {
            const int rowL = wid * 16 + lgrp * 4 + r;
            const int qi = q0 + rowL;
            if (qi < N_) {
                float o = O4[nf][r] / lreg[r];
                if (qi > 0) o += pqf[base + (size_t)qi * HD_ + d];
                aoutbf[(size_t)(b * N_ + qi) * (HEADS_ * HD_) + h * HD_ + d] = f2bfs(o);
            }
        }
    }
}

extern "C" void kernel_launch(void* const* d_in, const int* in_sizes, int n_in,
                              void* d_out, int out_size, void* d_ws, size_t ws_size,
                              hipStream_t stream) {
    const float* x    = (const float*)d_in[0];
    const float* Wqkv = (const float*)d_in[1];
    const float* bqkv = (const float*)d_in[2];
    const float* kq   = (const float*)d_in[3];
    const float* kk   = (const float*)d_in[4];
    const float* kv   = (const float*)d_in[5];
    const float* nqw  = (const float*)d_in[6];
    const float* nqb  = (const float*)d_in[7];
    const float* nkw  = (const float*)d_in[8];
    const float* nkb  = (const float*)d_in[9];
    const float* nvw  = (const float*)d_in[10];
    const float* nvb  = (const float*)d_in[11];
    const float* rpt  = (const float*)d_in[12];
    const float* rph  = (const float*)d_in[13];
    const float* rpw  = (const float*)d_in[14];
    const float* Wproj= (const float*)d_in[15];
    const float* bproj= (const float*)d_in[16];
    float* out = (float*)d_out;

    const size_t qkv_elems  = (size_t)M_ * QKVD;                  // 14.46M f32
    const size_t pool_elems = (size_t)B_ * HEADS_ * N_ * HD_;     // 4.82M
    float* qkvp = (float*)d_ws;                    // 57.8 MB
    float* pqf  = qkvp + qkv_elems;                // 19.3 MB (f32 pooled q)
    short* qbb  = (short*)(pqf + pool_elems);      // bf16 q/k/v: 28.9 MB
    short* kbb  = qbb + pool_elems;
    short* vbb  = kbb + pool_elems;
    short* abuf = vbb + pool_elems;                // [MPAD][768] bf16 (GEMM A staging)
    short* w1t  = abuf + (size_t)MPAD * IND;       // [2304][768] bf16 (W^T staging)
                                                   // total ~119 MB

    // GEMM1: qkv = x @ Wqkv + b
    f32_to_bf16_rows<<<MPAD, 256, 0, stream>>>(x, abuf, M_, IND);
    transpose_f32_bf16<<<dim3(QKVD / 32, IND / 32), 256, 0, stream>>>(Wqkv, w1t, IND, QKVD);
    gemm_mfma<<<dim3(QKVD / 128, MPAD / 128), 256, 0, stream>>>(abuf, w1t, bqkv, qkvp, M_, QKVD, IND);

    pool_ln<<<3 * B_ * HEADS_ * N_, 64, 0, stream>>>(qkvp, kq, kk, kv,
        nqw, nqb, nkw, nkb, nvw, nvb, pqf, qbb, kbb, vbb);

    // attention writes bf16 directly into abuf (rows >= M_ left stale; GEMM guards stores)
    attn_mfma<<<B_ * HEADS_ * NKT, 256, 0, stream>>>(qbb, kbb, vbb, pqf, rpt, rph, rpw, abuf);

    // GEMM2: out = attn_out @ Wproj + b
    transpose_f32_bf16<<<dim3(IND / 32, IND / 32), 256, 0, stream>>>(Wproj, w1t, IND, IND);
    gemm_mfma<<<dim3(IND / 128, MPAD / 128), 256, 0, stream>>>(abuf, w1t, bproj, out, M_, IND, IND);
}

// Round 6
// 682.633 us; speedup vs baseline: 11.3795x; 1.1046x over previous
//
#include <hip/hip_runtime.h>
#include <hip/hip_bf16.h>

#define B_ 4
#define N_ 1569
#define IND 768
#define HEADS_ 12
#define HD_ 64
#define T0_ 8
#define H0_ 14
#define W0_ 14
#define M_ (B_*N_)          // 6276
#define MPAD 6400           // 50*128
#define QKVD (3*IND)        // 2304
#define NKT 25              // ceil(1569/64)
#define PNT 50              // ceil(1569/32) pool n-tiles

typedef __attribute__((ext_vector_type(8))) short short8v;
typedef __attribute__((ext_vector_type(4))) float f32x4;

__device__ __forceinline__ short f2bfs(float f) {
    __hip_bfloat16 h = __float2bfloat16(f);
    return *reinterpret_cast<short*>(&h);
}

// ---- swizzled LDS helpers for [64 rows][64 bf16] tiles (128B rows) ----
// T2: byte ^= (row&7)<<4  — 16B-block XOR within 8-row stripes.
__device__ __forceinline__ short8v lds_read8(const short* base, int row, int byteInRow) {
    int byte = row * 128 + (byteInRow ^ ((row & 7) << 4));
    return *reinterpret_cast<const short8v*>(reinterpret_cast<const char*>(base) + byte);
}
__device__ __forceinline__ void lds_write8(short* base, int row, int byteInRow, short8v v) {
    int byte = row * 128 + (byteInRow ^ ((row & 7) << 4));
    *reinterpret_cast<short8v*>(reinterpret_cast<char*>(base) + byte) = v;
}
__device__ __forceinline__ void lds_write1(short* base, int row, int col, short v) {
    int byte = row * 128 + ((col * 2) ^ ((row & 7) << 4));
    *reinterpret_cast<short*>(reinterpret_cast<char*>(base) + byte) = v;
}

// ---------------- f32 -> bf16 row-wise convert with zero row padding ----------------
__global__ __launch_bounds__(256) void f32_to_bf16_rows(
        const float* __restrict__ src, short* __restrict__ dst, int rows, int cols) {
    const int r = blockIdx.x;
    const bool live = r < rows;
    for (int c = threadIdx.x; c < cols; c += 256) {
        float v = live ? src[(size_t)r * cols + c] : 0.f;
        dst[(size_t)r * cols + c] = f2bfs(v);
    }
}

// ---------------- W[K][N] f32 -> WT[N][K] bf16 ----------------
__global__ __launch_bounds__(256) void transpose_f32_bf16(
        const float* __restrict__ W, short* __restrict__ WT, int K, int N) {
    __shared__ float t[32][33];
    const int n0 = blockIdx.x * 32, k0 = blockIdx.y * 32;
    const int tx = threadIdx.x & 31, ty = threadIdx.x >> 5;
    #pragma unroll
    for (int p = 0; p < 4; p++)
        t[ty + 8 * p][tx] = W[(size_t)(k0 + ty + 8 * p) * N + n0 + tx];
    __syncthreads();
    #pragma unroll
    for (int p = 0; p < 4; p++)
        WT[(size_t)(n0 + ty + 8 * p) * K + k0 + tx] = f2bfs(t[tx][ty + 8 * p]);
}

// ---------------- MFMA GEMM: C[M,N] = A[Mpad,K](bf16) * BT[N,K](bf16)^T + bias ----------------
__global__ __launch_bounds__(256) void gemm_mfma(
        const short* __restrict__ A, const short* __restrict__ BT,
        const float* __restrict__ bias, float* __restrict__ C,
        int M, int N, int K) {
    __shared__ __align__(16) short As[128 * 32];
    __shared__ __align__(16) short Bs[128 * 32];
    const int tid = threadIdx.x;
    const int lane = tid & 63;
    const int wid = tid >> 6;
    const int bm = blockIdx.y * 128;
    const int bn = blockIdx.x * 128;
    const int wr = (wid >> 1) * 64, wc = (wid & 1) * 64;
    const int larow = lane & 15, lak = (lane >> 4) * 8;
    const int srow = tid >> 2, sk = (tid & 3) * 8;

    f32x4 acc[4][4];
    #pragma unroll
    for (int m = 0; m < 4; m++)
        #pragma unroll
        for (int n = 0; n < 4; n++) acc[m][n] = (f32x4){0.f, 0.f, 0.f, 0.f};

    for (int kt = 0; kt < K; kt += 32) {
        short8v a0 = *(const short8v*)(A + (size_t)(bm + srow) * K + kt + sk);
        short8v a1 = *(const short8v*)(A + (size_t)(bm + 64 + srow) * K + kt + sk);
        short8v b0 = *(const short8v*)(BT + (size_t)(bn + srow) * K + kt + sk);
        short8v b1 = *(const short8v*)(BT + (size_t)(bn + 64 + srow) * K + kt + sk);
        __syncthreads();
        *(short8v*)&As[srow * 32 + sk] = a0;
        *(short8v*)&As[(64 + srow) * 32 + sk] = a1;
        *(short8v*)&Bs[srow * 32 + sk] = b0;
        *(short8v*)&Bs[(64 + srow) * 32 + sk] = b1;
        __syncthreads();

        short8v af[4], bfv[4];
        #pragma unroll
        for (int m = 0; m < 4; m++)
            af[m] = *(const short8v*)&As[(wr + m * 16 + larow) * 32 + lak];
        #pragma unroll
        for (int n = 0; n < 4; n++)
            bfv[n] = *(const short8v*)&Bs[(wc + n * 16 + larow) * 32 + lak];
        #pragma unroll
        for (int m = 0; m < 4; m++)
            #pragma unroll
            for (int n = 0; n < 4; n++)
                acc[m][n] = __builtin_amdgcn_mfma_f32_16x16x32_bf16(af[m], bfv[n], acc[m][n], 0, 0, 0);
    }

    const int crow = (lane >> 4) * 4;
    const int ccol = lane & 15;
    #pragma unroll
    for (int n = 0; n < 4; n++) {
        const int col = bn + wc + n * 16 + ccol;
        const float bv = bias[col];
        #pragma unroll
        for (int m = 0; m < 4; m++) {
            #pragma unroll
            for (int r2 = 0; r2 < 4; r2++) {
                const int row = bm + wr + m * 16 + crow + r2;
                if (row < M) C[(size_t)row * N + col] = acc[m][n][r2] + bv;
            }
        }
    }
}

// ---------------- depthwise 3x3x3 conv pool + LayerNorm(64) ----------------
// 256 threads = 4 waves; block = (s,b,head, 32-n tile); each wave does 8 n's.
// Conv weights + LN params hoisted to registers once per block.
__global__ __launch_bounds__(256) void pool_ln(
        const float* __restrict__ qkv,
        const float* __restrict__ kq, const float* __restrict__ kk,
        const float* __restrict__ kv,
        const float* __restrict__ nqw, const float* __restrict__ nqb,
        const float* __restrict__ nkw, const float* __restrict__ nkb,
        const float* __restrict__ nvw, const float* __restrict__ nvb,
        float* __restrict__ pqf, short* __restrict__ qbb,
        short* __restrict__ kbb, short* __restrict__ vbb) {
    const int lane = threadIdx.x & 63;
    const int w = threadIdx.x >> 6;
    int bid = blockIdx.x;
    const int nt = bid % PNT; bid /= PNT;
    const int head = bid % HEADS_; bid /= HEADS_;
    const int b = bid % B_;
    const int s = bid / B_;

    const float* kern = (s == 0) ? kq : ((s == 1) ? kk : kv);
    const float* lw = (s == 0) ? nqw : ((s == 1) ? nkw : nvw);
    const float* lb = (s == 0) ? nqb : ((s == 1) ? nkb : nvb);
    short* bdst = (s == 0) ? qbb : ((s == 1) ? kbb : vbb);

    // hoist per-channel conv weights + LN params (reused for 8 outputs)
    float kw[27];
    #pragma unroll
    for (int i = 0; i < 27; i++) kw[i] = kern[lane * 27 + i];
    const float lwv = lw[lane], lbv = lb[lane];

    const size_t colbase = (size_t)s * IND + head * HD_ + lane;

    #pragma unroll 2
    for (int i = 0; i < 8; i++) {
        const int n = nt * 32 + w * 8 + i;      // wave-uniform
        if (n >= N_) break;
        float y;
        if (n == 0) {
            y = qkv[(size_t)(b * N_) * QKVD + colbase];
        } else {
            const int m = n - 1;
            const int ti = m / (H0_ * W0_);
            const int rr = m % (H0_ * W0_);
            const int hi = rr / W0_, wi = rr % W0_;
            float acc = 0.f;
            #pragma unroll
            for (int kt = 0; kt < 3; kt++) {
                int t2 = ti + kt - 1;
                if (t2 < 0 || t2 >= T0_) continue;
                #pragma unroll
                for (int kh = 0; kh < 3; kh++) {
                    int h2 = hi + kh - 1;
                    if (h2 < 0 || h2 >= H0_) continue;
                    #pragma unroll
                    for (int kw2 = 0; kw2 < 3; kw2++) {
                        int w2 = wi + kw2 - 1;
                        if (w2 < 0 || w2 >= W0_) continue;
                        int node = 1 + (t2 * H0_ + h2) * W0_ + w2;
                        float xv = qkv[(size_t)(b * N_ + node) * QKVD + colbase];
                        acc += xv * kw[(kt * 3 + kh) * 3 + kw2];
                    }
                }
            }
            y = acc;
        }
        // LayerNorm over the 64 channels = one wave
        float s1 = y;
        #pragma unroll
        for (int o = 32; o > 0; o >>= 1) s1 += __shfl_xor(s1, o);
        float mu = s1 * (1.f / 64.f);
        float diff = y - mu;
        float s2 = diff * diff;
        #pragma unroll
        for (int o = 32; o > 0; o >>= 1) s2 += __shfl_xor(s2, o);
        float var = s2 * (1.f / 64.f);
        float out = diff * rsqrtf(var + 1e-5f) * lwv + lbv;
        const size_t idx = ((size_t)((b * HEADS_ + head) * N_) + n) * HD_ + lane;
        bdst[idx] = f2bfs(out);
        if (s == 0) pqf[idx] = out;
    }
}

// ---------------- MFMA flash attention: 64-query tile, 4 waves, bf16 MFMA ----------------
__global__ __launch_bounds__(256) void attn_mfma(
        const short* __restrict__ qb, const short* __restrict__ kb,
        const short* __restrict__ vb, const float* __restrict__ pqf,
        const float* __restrict__ rpt, const float* __restrict__ rph,
        const float* __restrict__ rpw, short* __restrict__ aoutbf) {
    __shared__ __align__(16) short Qs[64 * 64];   // [q][d] swizzled
    __shared__ __align__(16) short Ks[64 * 64];   // [key][d] swizzled
    __shared__ __align__(16) short VT[64 * 64];   // [d][key] swizzled
    __shared__ __align__(16) short Ps[64 * 64];   // [q][key] swizzled
    __shared__ float relT[64][8];
    __shared__ float relH[64][14];
    __shared__ float relW[64][14];

    const int tid = threadIdx.x;
    const int lane = tid & 63;
    const int wid = tid >> 6;           // wave owns q rows wid*16..+15
    const int larow = lane & 15;
    const int lgrp = lane >> 4;

    int bid = blockIdx.x;
    const int qt = bid % NKT; bid /= NKT;
    const int h = bid % HEADS_;
    const int b = bid / HEADS_;
    const int q0 = qt * 64;
    const size_t base = (size_t)((b * HEADS_ + h) * N_) * HD_;

    // ---- stage Q tile (zero-padded) ----
    {
        const int row = tid >> 2, seg = tid & 3;
        const int qi = q0 + row;
        short8v v0 = {0,0,0,0,0,0,0,0}, v1 = v0;
        if (qi < N_) {
            const short8v* g = (const short8v*)(qb + base + (size_t)qi * HD_ + seg * 16);
            v0 = g[0]; v1 = g[1];
        }
        lds_write8(Qs, row, seg * 32, v0);
        lds_write8(Qs, row, seg * 32 + 16, v1);
    }

    // ---- rel-pos dot tables from f32 q ----
    #pragma unroll
    for (int it = 0; it < 9; it++) {           // 9*256 = 2304 = 64*36
        int flat = it * 256 + tid;
        int row = flat / 36, idx = flat - row * 36;
        int qi = q0 + row;
        bool valid = (qi >= 1 && qi < N_);
        int m = valid ? (qi - 1) : 0;
        int ti = m / 196, rr2 = m - ti * 196;
        int hi = rr2 / 14, wi = rr2 - hi * 14;
        const float* tab;
        float* dst;
        if (idx < 8)       { tab = rpt + (size_t)(ti - idx + 7) * HD_;          dst = &relT[row][idx]; }
        else if (idx < 22) { tab = rph + (size_t)(hi - (idx - 8) + 13) * HD_;   dst = &relH[row][idx - 8]; }
        else               { tab = rpw + (size_t)(wi - (idx - 22) + 13) * HD_;  dst = &relW[row][idx - 22]; }
        float acc = 0.f;
        if (valid) {
            const float4* qp = (const float4*)(pqf + base + (size_t)qi * HD_);
            const float4* tp = (const float4*)tab;
            #pragma unroll 4
            for (int dd = 0; dd < 16; dd++) {
                float4 a = qp[dd], t = tp[dd];
                acc += a.x * t.x + a.y * t.y + a.z * t.z + a.w * t.w;
            }
        }
        *dst = acc;
    }
    __syncthreads();

    // ---- hoist Q A-frags (constant across key tiles) ----
    short8v aq[2];
    #pragma unroll
    for (int ks = 0; ks < 2; ks++)
        aq[ks] = lds_read8(Qs, wid * 16 + larow, ks * 64 + lgrp * 16);

    float mreg[4], lreg[4];
    f32x4 O4[4];
    #pragma unroll
    for (int r = 0; r < 4; r++) { mreg[r] = -1e30f; lreg[r] = 0.f; }
    #pragma unroll
    for (int nf = 0; nf < 4; nf++) O4[nf] = (f32x4){0.f, 0.f, 0.f, 0.f};

    for (int kt = 0; kt < NKT; kt++) {
        __syncthreads();   // prior PV reads of Ks/VT done
        // ---- stage K tile ----
        {
            const int row = tid >> 2, seg = tid & 3;
            const int jg = kt * 64 + row;
            short8v v0 = {0,0,0,0,0,0,0,0}, v1 = v0;
            if (jg < N_) {
                const short8v* g = (const short8v*)(kb + base + (size_t)jg * HD_ + seg * 16);
                v0 = g[0]; v1 = g[1];
            }
            lds_write8(Ks, row, seg * 32, v0);
            lds_write8(Ks, row, seg * 32 + 16, v1);
        }
        // ---- stage V^T tile ----
        {
            const int d = tid & 63, kseg = tid >> 6;
            short tmp[16];
            #pragma unroll
            for (int jj = 0; jj < 16; jj++) {
                int kg = kt * 64 + kseg * 16 + jj;
                tmp[jj] = (kg < N_) ? vb[base + (size_t)kg * HD_ + d] : (short)0;
            }
            lds_write8(VT, d, kseg * 32, *(short8v*)&tmp[0]);
            lds_write8(VT, d, kseg * 32 + 16, *(short8v*)&tmp[8]);
        }
        __syncthreads();

        // ---- S = Q K^T via MFMA ----
        f32x4 s4[4];
        #pragma unroll
        for (int nf = 0; nf < 4; nf++) {
            f32x4 acc = (f32x4){0.f, 0.f, 0.f, 0.f};
            #pragma unroll
            for (int ks = 0; ks < 2; ks++) {
                short8v bk = lds_read8(Ks, nf * 16 + larow, ks * 64 + lgrp * 16);
                acc = __builtin_amdgcn_mfma_f32_16x16x32_bf16(aq[ks], bk, acc, 0, 0, 0);
            }
            s4[nf] = acc;
        }

        // ---- per-column rel-pos indices ----
        bool cvalid[4], cb[4];
        int tj[4], hj[4], wj[4];
        #pragma unroll
        for (int nf = 0; nf < 4; nf++) {
            int col = kt * 64 + nf * 16 + larow;
            cvalid[nf] = (col < N_);
            cb[nf] = (col >= 1 && col < N_);
            int mj = cb[nf] ? col - 1 : 0;
            tj[nf] = mj / 196; int rr3 = mj - tj[nf] * 196;
            hj[nf] = rr3 / 14; wj[nf] = rr3 - hj[nf] * 14;
        }

        // ---- online softmax on C/D layout (row = lgrp*4+r, col = nf*16+larow) ----
        float fac[4];
        #pragma unroll
        for (int r = 0; r < 4; r++) {
            const int rowL = wid * 16 + lgrp * 4 + r;
            const int qi = q0 + rowL;
            const bool qv = (qi >= 1 && qi < N_);
            float sv[4];
            #pragma unroll
            for (int nf = 0; nf < 4; nf++) {
                float x = s4[nf][r] * 0.125f;
                if (qv && cb[nf])
                    x += relT[rowL][tj[nf]] + relH[rowL][hj[nf]] + relW[rowL][wj[nf]];
                sv[nf] = cvalid[nf] ? x : -1e30f;
            }
            float rm = fmaxf(fmaxf(sv[0], sv[1]), fmaxf(sv[2], sv[3]));
            rm = fmaxf(rm, __shfl_xor(rm, 1));
            rm = fmaxf(rm, __shfl_xor(rm, 2));
            rm = fmaxf(rm, __shfl_xor(rm, 4));
            rm = fmaxf(rm, __shfl_xor(rm, 8));
            float mn = fmaxf(mreg[r], rm);
            float f = __expf(mreg[r] - mn);
            mreg[r] = mn;
            float ps = 0.f;
            #pragma unroll
            for (int nf = 0; nf < 4; nf++) {
                float p = __expf(sv[nf] - mn);
                ps += p;
                lds_write1(Ps, rowL, nf * 16 + larow, f2bfs(p));
            }
            ps += __shfl_xor(ps, 1); ps += __shfl_xor(ps, 2);
            ps += __shfl_xor(ps, 4); ps += __shfl_xor(ps, 8);
            lreg[r] = lreg[r] * f + ps;
            fac[r] = f;
        }
        #pragma unroll
        for (int nf = 0; nf < 4; nf++)
            #pragma unroll
            for (int r = 0; r < 4; r++) O4[nf][r] *= fac[r];
        __syncthreads();   // Ps visible (and ordered vs next restage)

        // ---- O += P V via MFMA ----
        short8v ap[2];
        #pragma unroll
        for (int ks = 0; ks < 2; ks++)
            ap[ks] = lds_read8(Ps, wid * 16 + larow, ks * 64 + lgrp * 16);
        #pragma unroll
        for (int nf = 0; nf < 4; nf++) {
            #pragma unroll
            for (int ks = 0; ks < 2; ks++) {
                short8v bv2 = lds_read8(VT, nf * 16 + larow, ks * 64 + lgrp * 16);
                O4[nf] = __builtin_amdgcn_mfma_f32_16x16x32_bf16(ap[ks], bv2, O4[nf], 0, 0, 0);
            }
        }
    }

    // ---- finalize: /l, +residual (f32 q), store bf16 into GEMM2 A-buffer ----
    #pragma unroll
    for (int nf = 0; nf < 4; nf++) {
        const int d = nf * 16 + larow;
        #pragma unroll
        for (int r = 0; r < 4; r++) {
            const int rowL = wid * 16 + lgrp * 4 + r;
            const int qi = q0 + rowL;
            if (qi < N_) {
                float o = O4[nf][r] / lreg[r];
                if (qi > 0) o += pqf[base + (size_t)qi * HD_ + d];
                aoutbf[(size_t)(b * N_ + qi) * (HEADS_ * HD_) + h * HD_ + d] = f2bfs(o);
            }
        }
    }
}

extern "C" void kernel_launch(void* const* d_in, const int* in_sizes, int n_in,
                              void* d_out, int out_size, void* d_ws, size_t ws_size,
                              hipStream_t stream) {
    const float* x    = (const float*)d_in[0];
    const float* Wqkv = (const float*)d_in[1];
    const float* bqkv = (const float*)d_in[2];
    const float* kq   = (const float*)d_in[3];
    const float* kk   = (const float*)d_in[4];
    const float* kv   = (const float*)d_in[5];
    const float* nqw  = (const float*)d_in[6];
    const float* nqb  = (const float*)d_in[7];
    const float* nkw  = (const float*)d_in[8];
    const float* nkb  = (const float*)d_in[9];
    const float* nvw  = (const float*)d_in[10];
    const float* nvb  = (const float*)d_in[11];
    const float* rpt  = (const float*)d_in[12];
    const float* rph  = (const float*)d_in[13];
    const float* rpw  = (const float*)d_in[14];
    const float* Wproj= (const float*)d_in[15];
    const float* bproj= (const float*)d_in[16];
    float* out = (float*)d_out;

    const size_t qkv_elems  = (size_t)M_ * QKVD;                  // 14.46M f32
    const size_t pool_elems = (size_t)B_ * HEADS_ * N_ * HD_;     // 4.82M
    float* qkvp = (float*)d_ws;                    // 57.8 MB
    float* pqf  = qkvp + qkv_elems;                // 19.3 MB (f32 pooled q)
    short* qbb  = (short*)(pqf + pool_elems);      // bf16 q/k/v: 28.9 MB
    short* kbb  = qbb + pool_elems;
    short* vbb  = kbb + pool_elems;
    short* abuf = vbb + pool_elems;                // [MPAD][768] bf16 (GEMM A staging)
    short* w1t  = abuf + (size_t)MPAD * IND;       // [2304][768] bf16 (W^T staging)
                                                   // total ~119 MB

    // GEMM1: qkv = x @ Wqkv + b
    f32_to_bf16_rows<<<MPAD, 256, 0, stream>>>(x, abuf, M_, IND);
    transpose_f32_bf16<<<dim3(QKVD / 32, IND / 32), 256, 0, stream>>>(Wqkv, w1t, IND, QKVD);
    gemm_mfma<<<dim3(QKVD / 128, MPAD / 128), 256, 0, stream>>>(abuf, w1t, bqkv, qkvp, M_, QKVD, IND);

    pool_ln<<<3 * B_ * HEADS_ * PNT, 256, 0, stream>>>(qkvp, kq, kk, kv,
        nqw, nqb, nkw, nkb, nvw, nvb, pqf, qbb, kbb, vbb);

    // attention writes bf16 directly into abuf (rows >= M_ left stale; GEMM guards stores)
    attn_mfma<<<B_ * HEADS_ * NKT, 256, 0, stream>>>(qbb, kbb, vbb, pqf, rpt, rph, rpw, abuf);

    // GEMM2: out = attn_out @ Wproj + b
    transpose_f32_bf16<<<dim3(IND / 32, IND / 32), 256, 0, stream>>>(Wproj, w1t, IND, IND);
    gemm_mfma<<<dim3(IND / 128, MPAD / 128), 256, 0, stream>>>(abuf, w1t, bproj, out, M_, IND, IND);
}

// Round 7
// 668.105 us; speedup vs baseline: 11.6270x; 1.0217x over previous
//
#include <hip/hip_runtime.h>
#include <hip/hip_bf16.h>

#define B_ 4
#define N_ 1569
#define IND 768
#define HEADS_ 12
#define HD_ 64
#define T0_ 8
#define H0_ 14
#define W0_ 14
#define M_ (B_*N_)          // 6276
#define MPAD 6400           // 50*128
#define QKVD (3*IND)        // 2304
#define NKT 25              // ceil(1569/64)
#define PNT 50              // ceil(1569/32) pool n-tiles
#define NPADK 1600          // padded key count (V^T columns)

typedef __attribute__((ext_vector_type(8))) short short8v;
typedef __attribute__((ext_vector_type(4))) float f32x4;

__device__ __forceinline__ short f2bfs(float f) {
    __hip_bfloat16 h = __float2bfloat16(f);
    return *reinterpret_cast<short*>(&h);
}

// async global->LDS 16B (HK-style address-space casts)
#define GLOAD_LDS16(gp, lp) \
    __builtin_amdgcn_global_load_lds( \
        (const __attribute__((address_space(1))) void*)(gp), \
        (__attribute__((address_space(3))) void*)(lp), 16, 0, 0)

// ---- swizzled LDS helpers for [64 rows][64 bf16] tiles (128B rows) ----
// T2: byte ^= (row&7)<<4  — 16B-block XOR within 8-row stripes.
__device__ __forceinline__ short8v lds_read8(const short* base, int row, int byteInRow) {
    int byte = row * 128 + (byteInRow ^ ((row & 7) << 4));
    return *reinterpret_cast<const short8v*>(reinterpret_cast<const char*>(base) + byte);
}
__device__ __forceinline__ void lds_write8(short* base, int row, int byteInRow, short8v v) {
    int byte = row * 128 + (byteInRow ^ ((row & 7) << 4));
    *reinterpret_cast<short8v*>(reinterpret_cast<char*>(base) + byte) = v;
}
__device__ __forceinline__ void lds_write1(short* base, int row, int col, short v) {
    int byte = row * 128 + ((col * 2) ^ ((row & 7) << 4));
    *reinterpret_cast<short*>(reinterpret_cast<char*>(base) + byte) = v;
}

// ---------------- f32 -> bf16 row-wise convert with zero row padding ----------------
__global__ __launch_bounds__(256) void f32_to_bf16_rows(
        const float* __restrict__ src, short* __restrict__ dst, int rows, int cols) {
    const int r = blockIdx.x;
    const bool live = r < rows;
    for (int c = threadIdx.x; c < cols; c += 256) {
        float v = live ? src[(size_t)r * cols + c] : 0.f;
        dst[(size_t)r * cols + c] = f2bfs(v);
    }
}

// ---------------- W[K][N] f32 -> WT[N][K] bf16 ----------------
__global__ __launch_bounds__(256) void transpose_f32_bf16(
        const float* __restrict__ W, short* __restrict__ WT, int K, int N) {
    __shared__ float t[32][33];
    const int n0 = blockIdx.x * 32, k0 = blockIdx.y * 32;
    const int tx = threadIdx.x & 31, ty = threadIdx.x >> 5;
    #pragma unroll
    for (int p = 0; p < 4; p++)
        t[ty + 8 * p][tx] = W[(size_t)(k0 + ty + 8 * p) * N + n0 + tx];
    __syncthreads();
    #pragma unroll
    for (int p = 0; p < 4; p++)
        WT[(size_t)(n0 + ty + 8 * p) * K + k0 + tx] = f2bfs(t[tx][ty + 8 * p]);
}

// ---------------- V natural [bh][n][d] -> V^T padded [bh][d][NPADK] ----------------
__global__ __launch_bounds__(256) void transpose_v_pad(
        const short* __restrict__ vbb, short* __restrict__ vtb) {
    __shared__ short t[64][65];
    int bid = blockIdx.x;
    const int nt = bid % NKT; bid /= NKT;
    const int bh = bid;                      // 0..47
    const int n0 = nt * 64;
    {
        const int r = threadIdx.x >> 2, seg = threadIdx.x & 3;
        const int n = n0 + r;
        short8v v0 = {0,0,0,0,0,0,0,0}, v1 = v0;
        if (n < N_) {
            const short8v* g = (const short8v*)(vbb + ((size_t)bh * N_ + n) * HD_ + seg * 16);
            v0 = g[0]; v1 = g[1];
        }
        #pragma unroll
        for (int j = 0; j < 8; j++) t[r][seg * 16 + j] = v0[j];
        #pragma unroll
        for (int j = 0; j < 8; j++) t[r][seg * 16 + 8 + j] = v1[j];
    }
    __syncthreads();
    {
        const int d = threadIdx.x >> 2, seg = threadIdx.x & 3;
        short tmp[16];
        #pragma unroll
        for (int j = 0; j < 16; j++) tmp[j] = t[seg * 16 + j][d];
        short8v* o = (short8v*)(vtb + ((size_t)bh * HD_ + d) * NPADK + n0 + seg * 16);
        o[0] = *(short8v*)&tmp[0];
        o[1] = *(short8v*)&tmp[8];
    }
}

// ---------------- MFMA GEMM: C[M,N] = A[Mpad,K](bf16) * BT[N,K](bf16)^T + bias ----------------
// 128x128 tile, BK=32, async global_load_lds staging (tid-linear LDS layout).
__global__ __launch_bounds__(256) void gemm_mfma(
        const short* __restrict__ A, const short* __restrict__ BT,
        const float* __restrict__ bias, float* __restrict__ C,
        int M, int N, int K) {
    __shared__ __align__(16) short As[128 * 32];
    __shared__ __align__(16) short Bs[128 * 32];
    const int tid = threadIdx.x;
    const int lane = tid & 63;
    const int wid = tid >> 6;
    const int bm = blockIdx.y * 128;
    const int bn = blockIdx.x * 128;
    const int wr = (wid >> 1) * 64, wc = (wid & 1) * 64;
    const int larow = lane & 15, lak = (lane >> 4) * 8;
    const int srow = tid >> 2, sk = (tid & 3) * 8;   // byte offset = tid*16 (lane-linear)

    f32x4 acc[4][4];
    #pragma unroll
    for (int m = 0; m < 4; m++)
        #pragma unroll
        for (int n = 0; n < 4; n++) acc[m][n] = (f32x4){0.f, 0.f, 0.f, 0.f};

    for (int kt = 0; kt < K; kt += 32) {
        __syncthreads();   // prior frag reads done before overwriting LDS
        GLOAD_LDS16(A  + (size_t)(bm + srow) * K + kt + sk,       As + srow * 32 + sk);
        GLOAD_LDS16(A  + (size_t)(bm + 64 + srow) * K + kt + sk,  As + (64 + srow) * 32 + sk);
        GLOAD_LDS16(BT + (size_t)(bn + srow) * K + kt + sk,       Bs + srow * 32 + sk);
        GLOAD_LDS16(BT + (size_t)(bn + 64 + srow) * K + kt + sk,  Bs + (64 + srow) * 32 + sk);
        __syncthreads();   // drains vmcnt -> LDS tiles complete

        short8v af[4], bfv[4];
        #pragma unroll
        for (int m = 0; m < 4; m++)
            af[m] = *(const short8v*)&As[(wr + m * 16 + larow) * 32 + lak];
        #pragma unroll
        for (int n = 0; n < 4; n++)
            bfv[n] = *(const short8v*)&Bs[(wc + n * 16 + larow) * 32 + lak];
        #pragma unroll
        for (int m = 0; m < 4; m++)
            #pragma unroll
            for (int n = 0; n < 4; n++)
                acc[m][n] = __builtin_amdgcn_mfma_f32_16x16x32_bf16(af[m], bfv[n], acc[m][n], 0, 0, 0);
    }

    const int crow = (lane >> 4) * 4;
    const int ccol = lane & 15;
    #pragma unroll
    for (int n = 0; n < 4; n++) {
        const int col = bn + wc + n * 16 + ccol;
        const float bv = bias[col];
        #pragma unroll
        for (int m = 0; m < 4; m++) {
            #pragma unroll
            for (int r2 = 0; r2 < 4; r2++) {
                const int row = bm + wr + m * 16 + crow + r2;
                if (row < M) C[(size_t)row * N + col] = acc[m][n][r2] + bv;
            }
        }
    }
}

// ---------------- depthwise 3x3x3 conv pool + LayerNorm(64) ----------------
__global__ __launch_bounds__(256) void pool_ln(
        const float* __restrict__ qkv,
        const float* __restrict__ kq, const float* __restrict__ kk,
        const float* __restrict__ kv,
        const float* __restrict__ nqw, const float* __restrict__ nqb,
        const float* __restrict__ nkw, const float* __restrict__ nkb,
        const float* __restrict__ nvw, const float* __restrict__ nvb,
        float* __restrict__ pqf, short* __restrict__ qbb,
        short* __restrict__ kbb, short* __restrict__ vbb) {
    const int lane = threadIdx.x & 63;
    const int w = threadIdx.x >> 6;
    int bid = blockIdx.x;
    const int nt = bid % PNT; bid /= PNT;
    const int head = bid % HEADS_; bid /= HEADS_;
    const int b = bid % B_;
    const int s = bid / B_;

    const float* kern = (s == 0) ? kq : ((s == 1) ? kk : kv);
    const float* lw = (s == 0) ? nqw : ((s == 1) ? nkw : nvw);
    const float* lb = (s == 0) ? nqb : ((s == 1) ? nkb : nvb);
    short* bdst = (s == 0) ? qbb : ((s == 1) ? kbb : vbb);

    float kw[27];
    #pragma unroll
    for (int i = 0; i < 27; i++) kw[i] = kern[lane * 27 + i];
    const float lwv = lw[lane], lbv = lb[lane];

    const size_t colbase = (size_t)s * IND + head * HD_ + lane;

    #pragma unroll 2
    for (int i = 0; i < 8; i++) {
        const int n = nt * 32 + w * 8 + i;
        if (n >= N_) break;
        float y;
        if (n == 0) {
            y = qkv[(size_t)(b * N_) * QKVD + colbase];
        } else {
            const int m = n - 1;
            const int ti = m / (H0_ * W0_);
            const int rr = m % (H0_ * W0_);
            const int hi = rr / W0_, wi = rr % W0_;
            float acc = 0.f;
            #pragma unroll
            for (int kt = 0; kt < 3; kt++) {
                int t2 = ti + kt - 1;
                if (t2 < 0 || t2 >= T0_) continue;
                #pragma unroll
                for (int kh = 0; kh < 3; kh++) {
                    int h2 = hi + kh - 1;
                    if (h2 < 0 || h2 >= H0_) continue;
                    #pragma unroll
                    for (int kw2 = 0; kw2 < 3; kw2++) {
                        int w2 = wi + kw2 - 1;
                        if (w2 < 0 || w2 >= W0_) continue;
                        int node = 1 + (t2 * H0_ + h2) * W0_ + w2;
                        float xv = qkv[(size_t)(b * N_ + node) * QKVD + colbase];
                        acc += xv * kw[(kt * 3 + kh) * 3 + kw2];
                    }
                }
            }
            y = acc;
        }
        float s1 = y;
        #pragma unroll
        for (int o = 32; o > 0; o >>= 1) s1 += __shfl_xor(s1, o);
        float mu = s1 * (1.f / 64.f);
        float diff = y - mu;
        float s2 = diff * diff;
        #pragma unroll
        for (int o = 32; o > 0; o >>= 1) s2 += __shfl_xor(s2, o);
        float var = s2 * (1.f / 64.f);
        float out = diff * rsqrtf(var + 1e-5f) * lwv + lbv;
        const size_t idx = ((size_t)((b * HEADS_ + head) * N_) + n) * HD_ + lane;
        bdst[idx] = f2bfs(out);
        if (s == 0) pqf[idx] = out;
    }
}

// ---------------- MFMA flash attention: 64-query tile, 4 waves, bf16 MFMA ----------------
__global__ __launch_bounds__(256) void attn_mfma(
        const short* __restrict__ qb, const short* __restrict__ kb,
        const short* __restrict__ vtb, const float* __restrict__ pqf,
        const float* __restrict__ rpt, const float* __restrict__ rph,
        const float* __restrict__ rpw, short* __restrict__ aoutbf) {
    __shared__ __align__(16) short Qs[64 * 64];   // [q][d] swizzled
    __shared__ __align__(16) short Ks[64 * 64];   // [key][d] swizzled
    __shared__ __align__(16) short VT[64 * 64];   // [d][key] swizzled
    __shared__ __align__(16) short Ps[64 * 64];   // [q][key] swizzled
    __shared__ float relT[64][8];
    __shared__ float relH[64][14];
    __shared__ float relW[64][14];

    const int tid = threadIdx.x;
    const int lane = tid & 63;
    const int wid = tid >> 6;           // wave owns q rows wid*16..+15
    const int larow = lane & 15;
    const int lgrp = lane >> 4;

    int bid = blockIdx.x;
    const int qt = bid % NKT; bid /= NKT;
    const int h = bid % HEADS_;
    const int b = bid / HEADS_;
    const int q0 = qt * 64;
    const int bh = b * HEADS_ + h;
    const size_t base = (size_t)bh * N_ * HD_;

    // ---- stage Q tile (zero-padded) ----
    {
        const int row = tid >> 2, seg = tid & 3;
        const int qi = q0 + row;
        short8v v0 = {0,0,0,0,0,0,0,0}, v1 = v0;
        if (qi < N_) {
            const short8v* g = (const short8v*)(qb + base + (size_t)qi * HD_ + seg * 16);
            v0 = g[0]; v1 = g[1];
        }
        lds_write8(Qs, row, seg * 32, v0);
        lds_write8(Qs, row, seg * 32 + 16, v1);
    }

    // ---- rel-pos dot tables from f32 q ----
    #pragma unroll
    for (int it = 0; it < 9; it++) {           // 9*256 = 2304 = 64*36
        int flat = it * 256 + tid;
        int row = flat / 36, idx = flat - row * 36;
        int qi = q0 + row;
        bool valid = (qi >= 1 && qi < N_);
        int m = valid ? (qi - 1) : 0;
        int ti = m / 196, rr2 = m - ti * 196;
        int hi = rr2 / 14, wi = rr2 - hi * 14;
        const float* tab;
        float* dst;
        if (idx < 8)       { tab = rpt + (size_t)(ti - idx + 7) * HD_;          dst = &relT[row][idx]; }
        else if (idx < 22) { tab = rph + (size_t)(hi - (idx - 8) + 13) * HD_;   dst = &relH[row][idx - 8]; }
        else               { tab = rpw + (size_t)(wi - (idx - 22) + 13) * HD_;  dst = &relW[row][idx - 22]; }
        float acc = 0.f;
        if (valid) {
            const float4* qp = (const float4*)(pqf + base + (size_t)qi * HD_);
            const float4* tp = (const float4*)tab;
            #pragma unroll 4
            for (int dd = 0; dd < 16; dd++) {
                float4 a = qp[dd], t = tp[dd];
                acc += a.x * t.x + a.y * t.y + a.z * t.z + a.w * t.w;
            }
        }
        *dst = acc;
    }
    __syncthreads();

    // ---- hoist Q A-frags (constant across key tiles) ----
    short8v aq[2];
    #pragma unroll
    for (int ks = 0; ks < 2; ks++)
        aq[ks] = lds_read8(Qs, wid * 16 + larow, ks * 64 + lgrp * 16);

    float mreg[4], lreg[4];
    f32x4 O4[4];
    #pragma unroll
    for (int r = 0; r < 4; r++) { mreg[r] = -1e30f; lreg[r] = 0.f; }
    #pragma unroll
    for (int nf = 0; nf < 4; nf++) O4[nf] = (f32x4){0.f, 0.f, 0.f, 0.f};

    for (int kt = 0; kt < NKT; kt++) {
        __syncthreads();   // prior PV reads of Ks/VT done
        // ---- stage K tile ----
        {
            const int row = tid >> 2, seg = tid & 3;
            const int jg = kt * 64 + row;
            short8v v0 = {0,0,0,0,0,0,0,0}, v1 = v0;
            if (jg < N_) {
                const short8v* g = (const short8v*)(kb + base + (size_t)jg * HD_ + seg * 16);
                v0 = g[0]; v1 = g[1];
            }
            lds_write8(Ks, row, seg * 32, v0);
            lds_write8(Ks, row, seg * 32 + 16, v1);
        }
        // ---- stage V^T tile from padded global V^T (coalesced b128) ----
        {
            const int d = tid >> 2, seg = tid & 3;
            const short8v* g = (const short8v*)(vtb + ((size_t)bh * HD_ + d) * NPADK + kt * 64 + seg * 16);
            lds_write8(VT, d, seg * 32, g[0]);
            lds_write8(VT, d, seg * 32 + 16, g[1]);
        }
        __syncthreads();

        // ---- S = Q K^T via MFMA ----
        f32x4 s4[4];
        #pragma unroll
        for (int nf = 0; nf < 4; nf++) {
            f32x4 acc = (f32x4){0.f, 0.f, 0.f, 0.f};
            #pragma unroll
            for (int ks = 0; ks < 2; ks++) {
                short8v bk = lds_read8(Ks, nf * 16 + larow, ks * 64 + lgrp * 16);
                acc = __builtin_amdgcn_mfma_f32_16x16x32_bf16(aq[ks], bk, acc, 0, 0, 0);
            }
            s4[nf] = acc;
        }

        // ---- per-column rel-pos indices ----
        bool cvalid[4], cb[4];
        int tj[4], hj[4], wj[4];
        #pragma unroll
        for (int nf = 0; nf < 4; nf++) {
            int col = kt * 64 + nf * 16 + larow;
            cvalid[nf] = (col < N_);
            cb[nf] = (col >= 1 && col < N_);
            int mj = cb[nf] ? col - 1 : 0;
            tj[nf] = mj / 196; int rr3 = mj - tj[nf] * 196;
            hj[nf] = rr3 / 14; wj[nf] = rr3 - hj[nf] * 14;
        }

        // ---- online softmax on C/D layout (row = lgrp*4+r, col = nf*16+larow) ----
        float fac[4];
        #pragma unroll
        for (int r = 0; r < 4; r++) {
            const int rowL = wid * 16 + lgrp * 4 + r;
            const int qi = q0 + rowL;
            const bool qv = (qi >= 1 && qi < N_);
            float sv[4];
            #pragma unroll
            for (int nf = 0; nf < 4; nf++) {
                float x = s4[nf][r] * 0.125f;
                if (qv && cb[nf])
                    x += relT[rowL][tj[nf]] + relH[rowL][hj[nf]] + relW[rowL][wj[nf]];
                sv[nf] = cvalid[nf] ? x : -1e30f;
            }
            float rm = fmaxf(fmaxf(sv[0], sv[1]), fmaxf(sv[2], sv[3]));
            rm = fmaxf(rm, __shfl_xor(rm, 1));
            rm = fmaxf(rm, __shfl_xor(rm, 2));
            rm = fmaxf(rm, __shfl_xor(rm, 4));
            rm = fmaxf(rm, __shfl_xor(rm, 8));
            float mn = fmaxf(mreg[r], rm);
            float f = __expf(mreg[r] - mn);
            mreg[r] = mn;
            float ps = 0.f;
            #pragma unroll
            for (int nf = 0; nf < 4; nf++) {
                float p = __expf(sv[nf] - mn);
                ps += p;
                lds_write1(Ps, rowL, nf * 16 + larow, f2bfs(p));
            }
            ps += __shfl_xor(ps, 1); ps += __shfl_xor(ps, 2);
            ps += __shfl_xor(ps, 4); ps += __shfl_xor(ps, 8);
            lreg[r] = lreg[r] * f + ps;
            fac[r] = f;
        }
        #pragma unroll
        for (int nf = 0; nf < 4; nf++)
            #pragma unroll
            for (int r = 0; r < 4; r++) O4[nf][r] *= fac[r];
        __syncthreads();   // Ps visible (and ordered vs next restage)

        // ---- O += P V via MFMA ----
        short8v ap[2];
        #pragma unroll
        for (int ks = 0; ks < 2; ks++)
            ap[ks] = lds_read8(Ps, wid * 16 + larow, ks * 64 + lgrp * 16);
        #pragma unroll
        for (int nf = 0; nf < 4; nf++) {
            #pragma unroll
            for (int ks = 0; ks < 2; ks++) {
                short8v bv2 = lds_read8(VT, nf * 16 + larow, ks * 64 + lgrp * 16);
                O4[nf] = __builtin_amdgcn_mfma_f32_16x16x32_bf16(ap[ks], bv2, O4[nf], 0, 0, 0);
            }
        }
    }

    // ---- finalize: /l, +residual (f32 q), store bf16 into GEMM2 A-buffer ----
    #pragma unroll
    for (int nf = 0; nf < 4; nf++) {
        const int d = nf * 16 + larow;
        #pragma unroll
        for (int r = 0; r < 4; r++) {
            const int rowL = wid * 16 + lgrp * 4 + r;
            const int qi = q0 + rowL;
            if (qi < N_) {
                float o = O4[nf][r] / lreg[r];
                if (qi > 0) o += pqf[base + (size_t)qi * HD_ + d];
                aoutbf[(size_t)(b * N_ + qi) * (HEADS_ * HD_) + h * HD_ + d] = f2bfs(o);
            }
        }
    }
}

extern "C" void kernel_launch(void* const* d_in, const int* in_sizes, int n_in,
                              void* d_out, int out_size, void* d_ws, size_t ws_size,
                              hipStream_t stream) {
    const float* x    = (const float*)d_in[0];
    const float* Wqkv = (const float*)d_in[1];
    const float* bqkv = (const float*)d_in[2];
    const float* kq   = (const float*)d_in[3];
    const float* kk   = (const float*)d_in[4];
    const float* kv   = (const float*)d_in[5];
    const float* nqw  = (const float*)d_in[6];
    const float* nqb  = (const float*)d_in[7];
    const float* nkw  = (const float*)d_in[8];
    const float* nkb  = (const float*)d_in[9];
    const float* nvw  = (const float*)d_in[10];
    const float* nvb  = (const float*)d_in[11];
    const float* rpt  = (const float*)d_in[12];
    const float* rph  = (const float*)d_in[13];
    const float* rpw  = (const float*)d_in[14];
    const float* Wproj= (const float*)d_in[15];
    const float* bproj= (const float*)d_in[16];
    float* out = (float*)d_out;

    const size_t qkv_elems  = (size_t)M_ * QKVD;                  // 14.46M f32
    const size_t pool_elems = (size_t)B_ * HEADS_ * N_ * HD_;     // 4.82M
    float* qkvp = (float*)d_ws;                    // 57.8 MB
    float* pqf  = qkvp + qkv_elems;                // 19.3 MB (f32 pooled q)
    short* qbb  = (short*)(pqf + pool_elems);      // bf16 q/k/v: 28.9 MB
    short* kbb  = qbb + pool_elems;
    short* vbb  = kbb + pool_elems;
    short* abuf = vbb + pool_elems;                // [MPAD][768] bf16 (GEMM A staging)
    short* w1t  = abuf + (size_t)MPAD * IND;       // [2304][768] bf16 (W^T staging)
    short* vtb  = w1t + (size_t)QKVD * IND;        // [48][64][1600] bf16 V^T padded
                                                   // total ~129 MB

    // GEMM1: qkv = x @ Wqkv + b
    f32_to_bf16_rows<<<MPAD, 256, 0, stream>>>(x, abuf, M_, IND);
    transpose_f32_bf16<<<dim3(QKVD / 32, IND / 32), 256, 0, stream>>>(Wqkv, w1t, IND, QKVD);
    gemm_mfma<<<dim3(QKVD / 128, MPAD / 128), 256, 0, stream>>>(abuf, w1t, bqkv, qkvp, M_, QKVD, IND);

    pool_ln<<<3 * B_ * HEADS_ * PNT, 256, 0, stream>>>(qkvp, kq, kk, kv,
        nqw, nqb, nkw, nkb, nvw, nvb, pqf, qbb, kbb, vbb);

    transpose_v_pad<<<B_ * HEADS_ * NKT, 256, 0, stream>>>(vbb, vtb);

    // attention writes bf16 directly into abuf (rows >= M_ stay zero from convert)
    attn_mfma<<<B_ * HEADS_ * NKT, 256, 0, stream>>>(qbb, kbb, vtb, pqf, rpt, rph, rpw, abuf);

    // GEMM2: out = attn_out @ Wproj + b
    transpose_f32_bf16<<<dim3(IND / 32, IND / 32), 256, 0, stream>>>(Wproj, w1t, IND, IND);
    gemm_mfma<<<dim3(IND / 128, MPAD / 128), 256, 0, stream>>>(abuf, w1t, bproj, out, M_, IND, IND);
}

// Round 8
// 567.778 us; speedup vs baseline: 13.6815x; 1.1767x over previous
//
#include <hip/hip_runtime.h>
#include <hip/hip_bf16.h>

#define B_ 4
#define N_ 1569
#define IND 768
#define HEADS_ 12
#define HD_ 64
#define T0_ 8
#define H0_ 14
#define W0_ 14
#define M_ (B_*N_)          // 6276
#define MPAD 6400           // 50*128
#define QKVD (3*IND)        // 2304
#define NKT 25              // ceil(1569/64)
#define PNT 50              // ceil(1569/32) pool n-tiles
#define NPADK 1600          // padded key count

typedef __attribute__((ext_vector_type(8))) short short8v;
typedef __attribute__((ext_vector_type(4))) float f32x4;

__device__ __forceinline__ short f2bfs(float f) {
    __hip_bfloat16 h = __float2bfloat16(f);
    return *reinterpret_cast<short*>(&h);
}
__device__ __forceinline__ unsigned int pk2bf(float a, float b) {
    return ((unsigned int)(unsigned short)f2bfs(b) << 16) | (unsigned short)f2bfs(a);
}

// ---- swizzled LDS helpers: 128B rows ([64][64] bf16) ----
__device__ __forceinline__ short8v lds_read8(const short* base, int row, int bir) {
    int byte = row * 128 + (bir ^ ((row & 7) << 4));
    return *reinterpret_cast<const short8v*>(reinterpret_cast<const char*>(base) + byte);
}
__device__ __forceinline__ void lds_write8(short* base, int row, int bir, short8v v) {
    int byte = row * 128 + (bir ^ ((row & 7) << 4));
    *reinterpret_cast<short8v*>(reinterpret_cast<char*>(base) + byte) = v;
}
__device__ __forceinline__ void lds_writeP(short* base, int row, int bir, unsigned int lo, unsigned int hi) {
    int byte = row * 128 + (bir ^ ((row & 7) << 4));
    uint2 v; v.x = lo; v.y = hi;
    *reinterpret_cast<uint2*>(reinterpret_cast<char*>(base) + byte) = v;
}
// ---- swizzled LDS helpers: 256B rows ([64][128] bf16 extended tiles) ----
__device__ __forceinline__ short8v lds_read8x(const short* base, int row, int bir) {
    int byte = row * 256 + (bir ^ ((row & 7) << 4));
    return *reinterpret_cast<const short8v*>(reinterpret_cast<const char*>(base) + byte);
}
__device__ __forceinline__ void lds_write8x(short* base, int row, int bir, short8v v) {
    int byte = row * 256 + (bir ^ ((row & 7) << 4));
    *reinterpret_cast<short8v*>(reinterpret_cast<char*>(base) + byte) = v;
}
__device__ __forceinline__ void lds_write1x(short* base, int row, int col, short v) {
    int byte = row * 256 + ((col * 2) ^ ((row & 7) << 4));
    *reinterpret_cast<short*>(reinterpret_cast<char*>(base) + byte) = v;
}

// ---------------- f32 -> bf16 row-wise convert with zero row padding ----------------
__global__ __launch_bounds__(256) void f32_to_bf16_rows(
        const float* __restrict__ src, short* __restrict__ dst, int rows, int cols) {
    const int r = blockIdx.x;
    const bool live = r < rows;
    for (int c = threadIdx.x; c < cols; c += 256) {
        float v = live ? src[(size_t)r * cols + c] : 0.f;
        dst[(size_t)r * cols + c] = f2bfs(v);
    }
}

// ---------------- W[K][N] f32 -> WT[N][K] bf16 ----------------
__global__ __launch_bounds__(256) void transpose_f32_bf16(
        const float* __restrict__ W, short* __restrict__ WT, int K, int N) {
    __shared__ float t[32][33];
    const int n0 = blockIdx.x * 32, k0 = blockIdx.y * 32;
    const int tx = threadIdx.x & 31, ty = threadIdx.x >> 5;
    #pragma unroll
    for (int p = 0; p < 4; p++)
        t[ty + 8 * p][tx] = W[(size_t)(k0 + ty + 8 * p) * N + n0 + tx];
    __syncthreads();
    #pragma unroll
    for (int p = 0; p < 4; p++)
        WT[(size_t)(n0 + ty + 8 * p) * K + k0 + tx] = f2bfs(t[tx][ty + 8 * p]);
}

// ---------------- V natural [bh][n][d] -> V^T padded [bh][d][NPADK] ----------------
__global__ __launch_bounds__(256) void transpose_v_pad(
        const short* __restrict__ vbb, short* __restrict__ vtb) {
    __shared__ short t[64][65];
    int bid = blockIdx.x;
    const int nt = bid % NKT; bid /= NKT;
    const int bh = bid;
    const int n0 = nt * 64;
    {
        const int r = threadIdx.x >> 2, seg = threadIdx.x & 3;
        const int n = n0 + r;
        short8v v0 = {0,0,0,0,0,0,0,0}, v1 = v0;
        if (n < N_) {
            const short8v* g = (const short8v*)(vbb + ((size_t)bh * N_ + n) * HD_ + seg * 16);
            v0 = g[0]; v1 = g[1];
        }
        #pragma unroll
        for (int j = 0; j < 8; j++) t[r][seg * 16 + j] = v0[j];
        #pragma unroll
        for (int j = 0; j < 8; j++) t[r][seg * 16 + 8 + j] = v1[j];
    }
    __syncthreads();
    {
        const int d = threadIdx.x >> 2, seg = threadIdx.x & 3;
        short tmp[16];
        #pragma unroll
        for (int j = 0; j < 16; j++) tmp[j] = t[seg * 16 + j][d];
        short8v* o = (short8v*)(vtb + ((size_t)bh * HD_ + d) * NPADK + n0 + seg * 16);
        o[0] = *(short8v*)&tmp[0];
        o[1] = *(short8v*)&tmp[8];
    }
}

// ---------------- rel-pos onehot extension table [NPADK][64] bf16 ----------------
// cols 0..7: onehot tj | 8..21: onehot hj | 22..35: onehot wj | 36: -1e30 if key invalid | rest 0
__global__ __launch_bounds__(64) void build_onehot(short* __restrict__ oneh) {
    const int kg = blockIdx.x;
    const int c = threadIdx.x;
    float v = 0.f;
    if (kg >= N_) {
        if (c == 36) v = -1e30f;
    } else if (kg >= 1) {
        int m = kg - 1;
        int tj = m / 196, rr = m - tj * 196;
        int hj = rr / 14, wj = rr - hj * 14;
        if (c == tj || c == 8 + hj || c == 22 + wj) v = 1.f;
    }
    oneh[(size_t)kg * 64 + c] = f2bfs(v);
}

// ---------------- MFMA GEMM: C[M,N] = A[Mpad,K](bf16) * BT[N,K](bf16)^T + bias ----------------
__global__ __launch_bounds__(256) void gemm_mfma(
        const short* __restrict__ A, const short* __restrict__ BT,
        const float* __restrict__ bias, float* __restrict__ C,
        int M, int N, int K) {
    __shared__ __align__(16) short As[128 * 32];
    __shared__ __align__(16) short Bs[128 * 32];
    const int tid = threadIdx.x;
    const int lane = tid & 63;
    const int wid = tid >> 6;
    const int bm = blockIdx.y * 128;
    const int bn = blockIdx.x * 128;
    const int wr = (wid >> 1) * 64, wc = (wid & 1) * 64;
    const int larow = lane & 15, lak = (lane >> 4) * 8;
    const int srow = tid >> 2, sk = (tid & 3) * 8;

    f32x4 acc[4][4];
    #pragma unroll
    for (int m = 0; m < 4; m++)
        #pragma unroll
        for (int n = 0; n < 4; n++) acc[m][n] = (f32x4){0.f, 0.f, 0.f, 0.f};

    for (int kt = 0; kt < K; kt += 32) {
        short8v a0 = *(const short8v*)(A + (size_t)(bm + srow) * K + kt + sk);
        short8v a1 = *(const short8v*)(A + (size_t)(bm + 64 + srow) * K + kt + sk);
        short8v b0 = *(const short8v*)(BT + (size_t)(bn + srow) * K + kt + sk);
        short8v b1 = *(const short8v*)(BT + (size_t)(bn + 64 + srow) * K + kt + sk);
        __syncthreads();
        *(short8v*)&As[srow * 32 + sk] = a0;
        *(short8v*)&As[(64 + srow) * 32 + sk] = a1;
        *(short8v*)&Bs[srow * 32 + sk] = b0;
        *(short8v*)&Bs[(64 + srow) * 32 + sk] = b1;
        __syncthreads();

        short8v af[4], bfv[4];
        #pragma unroll
        for (int m = 0; m < 4; m++)
            af[m] = *(const short8v*)&As[(wr + m * 16 + larow) * 32 + lak];
        #pragma unroll
        for (int n = 0; n < 4; n++)
            bfv[n] = *(const short8v*)&Bs[(wc + n * 16 + larow) * 32 + lak];
        #pragma unroll
        for (int m = 0; m < 4; m++)
            #pragma unroll
            for (int n = 0; n < 4; n++)
                acc[m][n] = __builtin_amdgcn_mfma_f32_16x16x32_bf16(af[m], bfv[n], acc[m][n], 0, 0, 0);
    }

    const int crow = (lane >> 4) * 4;
    const int ccol = lane & 15;
    #pragma unroll
    for (int n = 0; n < 4; n++) {
        const int col = bn + wc + n * 16 + ccol;
        const float bv = bias[col];
        #pragma unroll
        for (int m = 0; m < 4; m++) {
            #pragma unroll
            for (int r2 = 0; r2 < 4; r2++) {
                const int row = bm + wr + m * 16 + crow + r2;
                if (row < M) C[(size_t)row * N + col] = acc[m][n][r2] + bv;
            }
        }
    }
}

// ---------------- depthwise 3x3x3 conv pool + LayerNorm(64) ----------------
// qbb gets q PRE-SCALED by 0.125 (exact pow2); pqf stays unscaled f32.
__global__ __launch_bounds__(256) void pool_ln(
        const float* __restrict__ qkv,
        const float* __restrict__ kq, const float* __restrict__ kk,
        const float* __restrict__ kv,
        const float* __restrict__ nqw, const float* __restrict__ nqb,
        const float* __restrict__ nkw, const float* __restrict__ nkb,
        const float* __restrict__ nvw, const float* __restrict__ nvb,
        float* __restrict__ pqf, short* __restrict__ qbb,
        short* __restrict__ kbb, short* __restrict__ vbb) {
    const int lane = threadIdx.x & 63;
    const int w = threadIdx.x >> 6;
    int bid = blockIdx.x;
    const int nt = bid % PNT; bid /= PNT;
    const int head = bid % HEADS_; bid /= HEADS_;
    const int b = bid % B_;
    const int s = bid / B_;

    const float* kern = (s == 0) ? kq : ((s == 1) ? kk : kv);
    const float* lw = (s == 0) ? nqw : ((s == 1) ? nkw : nvw);
    const float* lb = (s == 0) ? nqb : ((s == 1) ? nkb : nvb);
    short* bdst = (s == 0) ? qbb : ((s == 1) ? kbb : vbb);

    float kw[27];
    #pragma unroll
    for (int i = 0; i < 27; i++) kw[i] = kern[lane * 27 + i];
    const float lwv = lw[lane], lbv = lb[lane];
    const float oscale = (s == 0) ? 0.125f : 1.f;

    const size_t colbase = (size_t)s * IND + head * HD_ + lane;

    #pragma unroll 2
    for (int i = 0; i < 8; i++) {
        const int n = nt * 32 + w * 8 + i;
        if (n >= N_) break;
        float y;
        if (n == 0) {
            y = qkv[(size_t)(b * N_) * QKVD + colbase];
        } else {
            const int m = n - 1;
            const int ti = m / (H0_ * W0_);
            const int rr = m % (H0_ * W0_);
            const int hi = rr / W0_, wi = rr % W0_;
            float acc = 0.f;
            #pragma unroll
            for (int kt = 0; kt < 3; kt++) {
                int t2 = ti + kt - 1;
                if (t2 < 0 || t2 >= T0_) continue;
                #pragma unroll
                for (int kh = 0; kh < 3; kh++) {
                    int h2 = hi + kh - 1;
                    if (h2 < 0 || h2 >= H0_) continue;
                    #pragma unroll
                    for (int kw2 = 0; kw2 < 3; kw2++) {
                        int w2 = wi + kw2 - 1;
                        if (w2 < 0 || w2 >= W0_) continue;
                        int node = 1 + (t2 * H0_ + h2) * W0_ + w2;
                        float xv = qkv[(size_t)(b * N_ + node) * QKVD + colbase];
                        acc += xv * kw[(kt * 3 + kh) * 3 + kw2];
                    }
                }
            }
            y = acc;
        }
        float s1 = y;
        #pragma unroll
        for (int o = 32; o > 0; o >>= 1) s1 += __shfl_xor(s1, o);
        float mu = s1 * (1.f / 64.f);
        float diff = y - mu;
        float s2 = diff * diff;
        #pragma unroll
        for (int o = 32; o > 0; o >>= 1) s2 += __shfl_xor(s2, o);
        float var = s2 * (1.f / 64.f);
        float out = diff * rsqrtf(var + 1e-5f) * lwv + lbv;
        const size_t idx = ((size_t)((b * HEADS_ + head) * N_) + n) * HD_ + lane;
        bdst[idx] = f2bfs(out * oscale);
        if (s == 0) pqf[idx] = out;
    }
}

// ---------------- MFMA flash attention: swapped QK^T + matrix-folded rel bias ----------------
// Extended d=128 operands: Q'=[0.125q | relT,relH,relW dots | 1.0 | 0], K'=[k | onehot | -1e30*invalid | 0].
// S^T = mfma(K',Q'): lane owns q-row (wid*16+larow), 16 key-scores in-register.
__global__ __launch_bounds__(256) void attn_mfma(
        const short* __restrict__ qb, const short* __restrict__ kb,
        const short* __restrict__ vtb, const short* __restrict__ oneh,
        const float* __restrict__ pqf,
        const float* __restrict__ rpt, const float* __restrict__ rph,
        const float* __restrict__ rpw, short* __restrict__ aoutbf) {
    __shared__ __align__(16) short Kse[64 * 128];  // [key][128d ext] swz256 (16KB)
    __shared__ __align__(16) short VT[64 * 64];    // [d][key] swz128 (8KB)
    __shared__ __align__(16) short QPs[64 * 128];  // Qext [64][128] swz256; Ps overlays first 8KB

    const int tid = threadIdx.x;
    const int lane = tid & 63;
    const int wid = tid >> 6;
    const int larow = lane & 15;
    const int lgrp = lane >> 4;

    // XCD-aware swizzle: 25 consecutive work-ids (one bh) land on one XCD
    int bid = (blockIdx.x & 7) * (B_ * HEADS_ * NKT / 8) + (blockIdx.x >> 3);
    const int qt = bid % NKT; bid /= NKT;
    const int h = bid % HEADS_;
    const int b = bid / HEADS_;
    const int q0 = qt * 64;
    const int bh = b * HEADS_ + h;
    const size_t base = (size_t)bh * N_ * HD_;

    short* Qse = QPs;
    short* Ps  = QPs;   // overlays Qse after B-frags hoisted

    // ---- stage Qext: cols 0..63 = prescaled q; ext half zero-filled ----
    {
        const int row = tid >> 2, seg = tid & 3;
        const int qi = q0 + row;
        short8v v0 = {0,0,0,0,0,0,0,0}, v1 = v0, z = v0;
        if (qi < N_) {
            const short8v* g = (const short8v*)(qb + base + (size_t)qi * HD_ + seg * 16);
            v0 = g[0]; v1 = g[1];
        }
        lds_write8x(Qse, row, seg * 32, v0);
        lds_write8x(Qse, row, seg * 32 + 16, v1);
        lds_write8x(Qse, row, 128 + seg * 32, z);
        lds_write8x(Qse, row, 128 + seg * 32 + 16, z);
    }
    __syncthreads();

    // ---- rel-pos dots -> Qext cols 64..99 (bf16); mask col 100 = 1.0 ----
    #pragma unroll
    for (int it = 0; it < 9; it++) {           // 9*256 = 2304 = 64*36
        int flat = it * 256 + tid;
        int row = flat / 36, idx = flat - row * 36;
        int qi = q0 + row;
        bool valid = (qi >= 1 && qi < N_);
        int m = valid ? (qi - 1) : 0;
        int ti = m / 196, rr2 = m - ti * 196;
        int hi = rr2 / 14, wi = rr2 - hi * 14;
        const float* tab;
        if (idx < 8)       tab = rpt + (size_t)(ti - idx + 7) * HD_;
        else if (idx < 22) tab = rph + (size_t)(hi - (idx - 8) + 13) * HD_;
        else               tab = rpw + (size_t)(wi - (idx - 22) + 13) * HD_;
        float acc = 0.f;
        if (valid) {
            const float4* qp = (const float4*)(pqf + base + (size_t)qi * HD_);
            const float4* tp = (const float4*)tab;
            #pragma unroll 4
            for (int dd = 0; dd < 16; dd++) {
                float4 a = qp[dd], t = tp[dd];
                acc += a.x * t.x + a.y * t.y + a.z * t.z + a.w * t.w;
            }
        }
        lds_write1x(Qse, row, 64 + idx, f2bfs(acc));
    }
    if (tid < 64) lds_write1x(Qse, tid, 100, (short)0x3F80);   // 1.0 bf16
    __syncthreads();

    // ---- hoist Q' B-frags (4 k-steps of 32) ----
    short8v bq[4];
    #pragma unroll
    for (int ks = 0; ks < 4; ks++)
        bq[ks] = lds_read8x(Qse, wid * 16 + larow, ks * 64 + lgrp * 16);

    float m_ = -1e30f, l_ = 0.f;
    f32x4 O4[4];
    #pragma unroll
    for (int nf = 0; nf < 4; nf++) O4[nf] = (f32x4){0.f, 0.f, 0.f, 0.f};

    for (int kt = 0; kt < NKT; kt++) {
        __syncthreads();   // prior tile reads done (also covers bq hoist / Ps overlay)
        // ---- stage K' ext tile ----
        {
            const int row = tid >> 2, seg = tid & 3;
            const int jg = kt * 64 + row;
            short8v k0 = {0,0,0,0,0,0,0,0}, k1 = k0;
            if (jg < N_) {
                const short8v* g = (const short8v*)(kb + base + (size_t)jg * HD_ + seg * 16);
                k0 = g[0]; k1 = g[1];
            }
            lds_write8x(Kse, row, seg * 32, k0);
            lds_write8x(Kse, row, seg * 32 + 16, k1);
            const short8v* oh = (const short8v*)(oneh + (size_t)jg * 64 + seg * 16);
            lds_write8x(Kse, row, 128 + seg * 32, oh[0]);
            lds_write8x(Kse, row, 128 + seg * 32 + 16, oh[1]);
            // ---- stage V^T tile (coalesced from padded global V^T) ----
            const short8v* gv = (const short8v*)(vtb + ((size_t)bh * HD_ + row) * NPADK + kt * 64 + seg * 16);
            lds_write8(VT, row, seg * 32, gv[0]);
            lds_write8(VT, row, seg * 32 + 16, gv[1]);
        }
        __syncthreads();

        // ---- S^T = K' Q'^T via MFMA (bias+mask folded in) ----
        f32x4 s4[4];
        #pragma unroll
        for (int nf = 0; nf < 4; nf++) {
            f32x4 acc = (f32x4){0.f, 0.f, 0.f, 0.f};
            #pragma unroll
            for (int ks = 0; ks < 4; ks++) {
                short8v ak = lds_read8x(Kse, nf * 16 + larow, ks * 64 + lgrp * 16);
                acc = __builtin_amdgcn_mfma_f32_16x16x32_bf16(ak, bq[ks], acc, 0, 0, 0);
            }
            s4[nf] = acc;
        }

        // ---- in-lane online softmax (lane owns q-row wid*16+larow) ----
        float rm = -1e30f;
        #pragma unroll
        for (int nf = 0; nf < 4; nf++)
            #pragma unroll
            for (int r = 0; r < 4; r++) rm = fmaxf(rm, s4[nf][r]);
        rm = fmaxf(rm, __shfl_xor(rm, 16));
        rm = fmaxf(rm, __shfl_xor(rm, 32));
        float mn = fmaxf(m_, rm);
        float fac = __expf(m_ - mn);
        m_ = mn;
        float p[4][4];
        float ps = 0.f;
        #pragma unroll
        for (int nf = 0; nf < 4; nf++)
            #pragma unroll
            for (int r = 0; r < 4; r++) {
                float e = __expf(s4[nf][r] - mn);
                p[nf][r] = e; ps += e;
            }
        ps += __shfl_xor(ps, 16);
        ps += __shfl_xor(ps, 32);
        l_ = l_ * fac + ps;

        // ---- P rows -> LDS (4x ds_write_b64, conflict-light) ----
        const int prow = wid * 16 + larow;
        #pragma unroll
        for (int nf = 0; nf < 4; nf++)
            lds_writeP(Ps, prow, nf * 32 + lgrp * 8,
                       pk2bf(p[nf][0], p[nf][1]), pk2bf(p[nf][2], p[nf][3]));

        // ---- O rescale (factors via shfl into O's layout) ----
        float facr[4];
        #pragma unroll
        for (int r = 0; r < 4; r++) facr[r] = __shfl(fac, lgrp * 4 + r);
        #pragma unroll
        for (int nf = 0; nf < 4; nf++)
            #pragma unroll
            for (int r = 0; r < 4; r++) O4[nf][r] *= facr[r];

        // ---- O += P V (same-wave P produce/consume: no barrier needed) ----
        short8v ap[2];
        ap[0] = lds_read8(Ps, prow, lgrp * 16);
        ap[1] = lds_read8(Ps, prow, 64 + lgrp * 16);
        #pragma unroll
        for (int nf = 0; nf < 4; nf++) {
            #pragma unroll
            for (int ks = 0; ks < 2; ks++) {
                short8v bv2 = lds_read8(VT, nf * 16 + larow, ks * 64 + lgrp * 16);
                O4[nf] = __builtin_amdgcn_mfma_f32_16x16x32_bf16(ap[ks], bv2, O4[nf], 0, 0, 0);
            }
        }
    }

    // ---- finalize: /l, +residual (unscaled f32 q), store bf16 ----
    float linv[4];
    #pragma unroll
    for (int r = 0; r < 4; r++) linv[r] = 1.f / __shfl(l_, lgrp * 4 + r);
    #pragma unroll
    for (int nf = 0; nf < 4; nf++) {
        const int d = nf * 16 + larow;
        #pragma unroll
        for (int r = 0; r < 4; r++) {
            const int rowL = wid * 16 + lgrp * 4 + r;
            const int qi = q0 + rowL;
            if (qi < N_) {
                float o = O4[nf][r] * linv[r];
                if (qi > 0) o += pqf[base + (size_t)qi * HD_ + d];
                aoutbf[(size_t)(b * N_ + qi) * (HEADS_ * HD_) + h * HD_ + d] = f2bfs(o);
            }
        }
    }
}

extern "C" void kernel_launch(void* const* d_in, const int* in_sizes, int n_in,
                              void* d_out, int out_size, void* d_ws, size_t ws_size,
                              hipStream_t stream) {
    const float* x    = (const float*)d_in[0];
    const float* Wqkv = (const float*)d_in[1];
    const float* bqkv = (const float*)d_in[2];
    const float* kq   = (const float*)d_in[3];
    const float* kk   = (const float*)d_in[4];
    const float* kv   = (const float*)d_in[5];
    const float* nqw  = (const float*)d_in[6];
    const float* nqb  = (const float*)d_in[7];
    const float* nkw  = (const float*)d_in[8];
    const float* nkb  = (const float*)d_in[9];
    const float* nvw  = (const float*)d_in[10];
    const float* nvb  = (const float*)d_in[11];
    const float* rpt  = (const float*)d_in[12];
    const float* rph  = (const float*)d_in[13];
    const float* rpw  = (const float*)d_in[14];
    const float* Wproj= (const float*)d_in[15];
    const float* bproj= (const float*)d_in[16];
    float* out = (float*)d_out;

    const size_t qkv_elems  = (size_t)M_ * QKVD;                  // 14.46M f32
    const size_t pool_elems = (size_t)B_ * HEADS_ * N_ * HD_;     // 4.82M
    float* qkvp = (float*)d_ws;                    // 57.8 MB
    float* pqf  = qkvp + qkv_elems;                // 19.3 MB (f32 pooled q, unscaled)
    short* qbb  = (short*)(pqf + pool_elems);      // bf16 q(*0.125)/k/v
    short* kbb  = qbb + pool_elems;
    short* vbb  = kbb + pool_elems;
    short* abuf = vbb + pool_elems;                // [MPAD][768] bf16
    short* w1t  = abuf + (size_t)MPAD * IND;       // [2304][768] bf16
    short* vtb  = w1t + (size_t)QKVD * IND;        // [48][64][1600] bf16
    short* oneh = vtb + (size_t)B_ * HEADS_ * HD_ * NPADK;  // [1600][64] bf16 (~200KB)

    // GEMM1: qkv = x @ Wqkv + b
    f32_to_bf16_rows<<<MPAD, 256, 0, stream>>>(x, abuf, M_, IND);
    transpose_f32_bf16<<<dim3(QKVD / 32, IND / 32), 256, 0, stream>>>(Wqkv, w1t, IND, QKVD);
    build_onehot<<<NPADK, 64, 0, stream>>>(oneh);
    gemm_mfma<<<dim3(QKVD / 128, MPAD / 128), 256, 0, stream>>>(abuf, w1t, bqkv, qkvp, M_, QKVD, IND);

    pool_ln<<<3 * B_ * HEADS_ * PNT, 256, 0, stream>>>(qkvp, kq, kk, kv,
        nqw, nqb, nkw, nkb, nvw, nvb, pqf, qbb, kbb, vbb);

    transpose_v_pad<<<B_ * HEADS_ * NKT, 256, 0, stream>>>(vbb, vtb);

    attn_mfma<<<B_ * HEADS_ * NKT, 256, 0, stream>>>(qbb, kbb, vtb, oneh, pqf, rpt, rph, rpw, abuf);

    // GEMM2: out = attn_out @ Wproj + b
    transpose_f32_bf16<<<dim3(IND / 32, IND / 32), 256, 0, stream>>>(Wproj, w1t, IND, IND);
    gemm_mfma<<<dim3(IND / 128, MPAD / 128), 256, 0, stream>>>(abuf, w1t, bproj, out, M_, IND, IND);
}

// Round 9
// 391.829 us; speedup vs baseline: 19.8251x; 1.4490x over previous
//
#include <hip/hip_runtime.h>
#include <hip/hip_bf16.h>

#define B_ 4
#define N_ 1569
#define IND 768
#define HEADS_ 12
#define HD_ 64
#define T0_ 8
#define H0_ 14
#define W0_ 14
#define M_ (B_*N_)          // 6276
#define MPAD 6400           // 50*128
#define QKVD (3*IND)        // 2304
#define NKT 25              // ceil(1569/64)
#define NPADK 1600          // padded key count
#define PBLK (3*B_*HEADS_*T0_)   // 1152 pool blocks

typedef __attribute__((ext_vector_type(8))) short short8v;
typedef __attribute__((ext_vector_type(4))) float f32x4;

__device__ __forceinline__ short f2bfs(float f) {
    __hip_bfloat16 h = __float2bfloat16(f);
    return *reinterpret_cast<short*>(&h);
}
__device__ __forceinline__ unsigned int pk2bf(float a, float b) {
    return ((unsigned int)(unsigned short)f2bfs(b) << 16) | (unsigned short)f2bfs(a);
}
__device__ __forceinline__ float bfu2f_lo(unsigned int u) {
    union { unsigned int i; float f; } x; x.i = u << 16; return x.f;
}
__device__ __forceinline__ float bfu2f_hi(unsigned int u) {
    union { unsigned int i; float f; } x; x.i = u & 0xFFFF0000u; return x.f;
}

// ---- swizzled LDS helpers: 128B rows ([64][64] bf16) ----
__device__ __forceinline__ short8v lds_read8(const short* base, int row, int bir) {
    int byte = row * 128 + (bir ^ ((row & 7) << 4));
    return *reinterpret_cast<const short8v*>(reinterpret_cast<const char*>(base) + byte);
}
__device__ __forceinline__ void lds_write8(short* base, int row, int bir, short8v v) {
    int byte = row * 128 + (bir ^ ((row & 7) << 4));
    *reinterpret_cast<short8v*>(reinterpret_cast<char*>(base) + byte) = v;
}
__device__ __forceinline__ void lds_writeP(short* base, int row, int bir, unsigned int lo, unsigned int hi) {
    int byte = row * 128 + (bir ^ ((row & 7) << 4));
    uint2 v; v.x = lo; v.y = hi;
    *reinterpret_cast<uint2*>(reinterpret_cast<char*>(base) + byte) = v;
}
// ---- swizzled LDS helpers: 256B rows ([64][128] bf16 extended tiles) ----
__device__ __forceinline__ short8v lds_read8x(const short* base, int row, int bir) {
    int byte = row * 256 + (bir ^ ((row & 7) << 4));
    return *reinterpret_cast<const short8v*>(reinterpret_cast<const char*>(base) + byte);
}
__device__ __forceinline__ void lds_write8x(short* base, int row, int bir, short8v v) {
    int byte = row * 256 + (bir ^ ((row & 7) << 4));
    *reinterpret_cast<short8v*>(reinterpret_cast<char*>(base) + byte) = v;
}
__device__ __forceinline__ void lds_write1x(short* base, int row, int col, short v) {
    int byte = row * 256 + ((col * 2) ^ ((row & 7) << 4));
    *reinterpret_cast<short*>(reinterpret_cast<char*>(base) + byte) = v;
}

// ---------------- f32 -> bf16 row-wise convert with zero row padding ----------------
__global__ __launch_bounds__(256) void f32_to_bf16_rows(
        const float* __restrict__ src, short* __restrict__ dst, int rows, int cols) {
    const int r = blockIdx.x;
    const bool live = r < rows;
    for (int c = threadIdx.x; c < cols; c += 256) {
        float v = live ? src[(size_t)r * cols + c] : 0.f;
        dst[(size_t)r * cols + c] = f2bfs(v);
    }
}

// ---------------- W[K][N] f32 -> WT[N][K] bf16 ----------------
__global__ __launch_bounds__(256) void transpose_f32_bf16(
        const float* __restrict__ W, short* __restrict__ WT, int K, int N) {
    __shared__ float t[32][33];
    const int n0 = blockIdx.x * 32, k0 = blockIdx.y * 32;
    const int tx = threadIdx.x & 31, ty = threadIdx.x >> 5;
    #pragma unroll
    for (int p = 0; p < 4; p++)
        t[ty + 8 * p][tx] = W[(size_t)(k0 + ty + 8 * p) * N + n0 + tx];
    __syncthreads();
    #pragma unroll
    for (int p = 0; p < 4; p++)
        WT[(size_t)(n0 + ty + 8 * p) * K + k0 + tx] = f2bfs(t[tx][ty + 8 * p]);
}

// ---------------- V natural [bh][n][d] -> V^T padded [bh][d][NPADK] ----------------
__global__ __launch_bounds__(256) void transpose_v_pad(
        const short* __restrict__ vbb, short* __restrict__ vtb) {
    __shared__ short t[64][65];
    int bid = blockIdx.x;
    const int nt = bid % NKT; bid /= NKT;
    const int bh = bid;
    const int n0 = nt * 64;
    {
        const int r = threadIdx.x >> 2, seg = threadIdx.x & 3;
        const int n = n0 + r;
        short8v v0 = {0,0,0,0,0,0,0,0}, v1 = v0;
        if (n < N_) {
            const short8v* g = (const short8v*)(vbb + ((size_t)bh * N_ + n) * HD_ + seg * 16);
            v0 = g[0]; v1 = g[1];
        }
        #pragma unroll
        for (int j = 0; j < 8; j++) t[r][seg * 16 + j] = v0[j];
        #pragma unroll
        for (int j = 0; j < 8; j++) t[r][seg * 16 + 8 + j] = v1[j];
    }
    __syncthreads();
    {
        const int d = threadIdx.x >> 2, seg = threadIdx.x & 3;
        short tmp[16];
        #pragma unroll
        for (int j = 0; j < 16; j++) tmp[j] = t[seg * 16 + j][d];
        short8v* o = (short8v*)(vtb + ((size_t)bh * HD_ + d) * NPADK + n0 + seg * 16);
        o[0] = *(short8v*)&tmp[0];
        o[1] = *(short8v*)&tmp[8];
    }
}

// ---------------- rel-pos onehot extension table [NPADK][64] bf16 ----------------
__global__ __launch_bounds__(64) void build_onehot(short* __restrict__ oneh) {
    const int kg = blockIdx.x;
    const int c = threadIdx.x;
    float v = 0.f;
    if (kg >= N_) {
        if (c == 36) v = -1e30f;
    } else if (kg >= 1) {
        int m = kg - 1;
        int tj = m / 196, rr = m - tj * 196;
        int hj = rr / 14, wj = rr - hj * 14;
        if (c == tj || c == 8 + hj || c == 22 + wj) v = 1.f;
    }
    oneh[(size_t)kg * 64 + c] = f2bfs(v);
}

// ---------------- MFMA GEMM: C[M,N] = A[Mpad,K](bf16) * BT[N,K](bf16)^T + bias ----------------
template<typename TOUT>
__global__ __launch_bounds__(256) void gemm_mfma(
        const short* __restrict__ A, const short* __restrict__ BT,
        const float* __restrict__ bias, TOUT* __restrict__ C,
        int M, int N, int K) {
    __shared__ __align__(16) short As[128 * 32];
    __shared__ __align__(16) short Bs[128 * 32];
    const int tid = threadIdx.x;
    const int lane = tid & 63;
    const int wid = tid >> 6;
    const int bm = blockIdx.y * 128;
    const int bn = blockIdx.x * 128;
    const int wr = (wid >> 1) * 64, wc = (wid & 1) * 64;
    const int larow = lane & 15, lak = (lane >> 4) * 8;
    const int srow = tid >> 2, sk = (tid & 3) * 8;

    f32x4 acc[4][4];
    #pragma unroll
    for (int m = 0; m < 4; m++)
        #pragma unroll
        for (int n = 0; n < 4; n++) acc[m][n] = (f32x4){0.f, 0.f, 0.f, 0.f};

    for (int kt = 0; kt < K; kt += 32) {
        short8v a0 = *(const short8v*)(A + (size_t)(bm + srow) * K + kt + sk);
        short8v a1 = *(const short8v*)(A + (size_t)(bm + 64 + srow) * K + kt + sk);
        short8v b0 = *(const short8v*)(BT + (size_t)(bn + srow) * K + kt + sk);
        short8v b1 = *(const short8v*)(BT + (size_t)(bn + 64 + srow) * K + kt + sk);
        __syncthreads();
        *(short8v*)&As[srow * 32 + sk] = a0;
        *(short8v*)&As[(64 + srow) * 32 + sk] = a1;
        *(short8v*)&Bs[srow * 32 + sk] = b0;
        *(short8v*)&Bs[(64 + srow) * 32 + sk] = b1;
        __syncthreads();

        short8v af[4], bfv[4];
        #pragma unroll
        for (int m = 0; m < 4; m++)
            af[m] = *(const short8v*)&As[(wr + m * 16 + larow) * 32 + lak];
        #pragma unroll
        for (int n = 0; n < 4; n++)
            bfv[n] = *(const short8v*)&Bs[(wc + n * 16 + larow) * 32 + lak];
        #pragma unroll
        for (int m = 0; m < 4; m++)
            #pragma unroll
            for (int n = 0; n < 4; n++)
                acc[m][n] = __builtin_amdgcn_mfma_f32_16x16x32_bf16(af[m], bfv[n], acc[m][n], 0, 0, 0);
    }

    const int crow = (lane >> 4) * 4;
    const int ccol = lane & 15;
    #pragma unroll
    for (int n = 0; n < 4; n++) {
        const int col = bn + wc + n * 16 + ccol;
        const float bv = bias[col];
        #pragma unroll
        for (int m = 0; m < 4; m++) {
            #pragma unroll
            for (int r2 = 0; r2 < 4; r2++) {
                const int row = bm + wr + m * 16 + crow + r2;
                if (row < M) {
                    float v = acc[m][n][r2] + bv;
                    if constexpr (sizeof(TOUT) == 2) C[(size_t)row * N + col] = f2bfs(v);
                    else                             C[(size_t)row * N + col] = v;
                }
            }
        }
    }
}

// ---------------- LDS-staged depthwise 3x3x3 conv pool + LayerNorm(64) ----------------
// block = (s, b, head, t-plane); stage t-1..t+1 planes (bf16, zero t-halo) in LDS.
// Wave handles node PAIRS: lanes 0-31 -> node A, 32-63 -> node B; 2 channels/lane.
__global__ __launch_bounds__(256) void pool_ln(
        const short* __restrict__ qkvb,
        const float* __restrict__ kq, const float* __restrict__ kk,
        const float* __restrict__ kv,
        const float* __restrict__ nqw, const float* __restrict__ nqb,
        const float* __restrict__ nkw, const float* __restrict__ nkb,
        const float* __restrict__ nvw, const float* __restrict__ nvb,
        float* __restrict__ pqf, short* __restrict__ qbb,
        short* __restrict__ kbb, short* __restrict__ vbb) {
    __shared__ __align__(16) short sp[3 * 196 * 64];   // 75,264 B

    const int tid = threadIdx.x;
    const int lane = tid & 63;
    const int wid = tid >> 6;
    const int li = lane & 31;          // channel-pair index (ch 2li, 2li+1)
    const int halfB = lane >> 5;       // 0: node A, 1: node B

    // XCD swizzle: 1152 % 8 == 0 -> bijective; t innermost keeps plane-sharers together
    int bid = (blockIdx.x & 7) * (PBLK / 8) + (blockIdx.x >> 3);
    const int t = bid & 7; bid >>= 3;
    const int head = bid % HEADS_; bid /= HEADS_;
    const int b = bid % B_;
    const int s = bid / B_;

    const float* kern = (s == 0) ? kq : ((s == 1) ? kk : kv);
    const float* lw = (s == 0) ? nqw : ((s == 1) ? nkw : nvw);
    const float* lb = (s == 0) ? nqb : ((s == 1) ? nkb : nvb);
    short* bdst = (s == 0) ? qbb : ((s == 1) ? kbb : vbb);

    // per-channel conv weights + LN params (2 channels per thread)
    float kwA[27], kwB[27];
    #pragma unroll
    for (int i = 0; i < 27; i++) {
        kwA[i] = kern[(2 * li) * 27 + i];
        kwB[i] = kern[(2 * li + 1) * 27 + i];
    }
    const float lw0 = lw[2 * li], lw1 = lw[2 * li + 1];
    const float lb0 = lb[2 * li], lb1 = lb[2 * li + 1];
    const float oscale = (s == 0) ? 0.125f : 1.f;

    const int colbase = s * IND + head * HD_;

    // ---- stage 3 planes (linear copy, zero t-halo) ----
    for (int c = tid; c < 3 * 196 * 8; c += 256) {
        const int p = c / 1568, rem = c - p * 1568;
        const int t2 = t - 1 + p;
        short8v v = {0,0,0,0,0,0,0,0};
        if (t2 >= 0 && t2 < T0_) {
            const int node = rem >> 3, seg = rem & 7;
            v = *(const short8v*)(qkvb +
                (size_t)(b * N_ + 1 + t2 * 196 + node) * QKVD + colbase + seg * 8);
        }
        *(short8v*)&sp[c * 8] = v;
    }
    __syncthreads();

    const size_t obase = (size_t)(b * HEADS_ + head) * N_ * HD_ + 2 * li;

    // ---- 98 node pairs across 4 waves ----
    for (int pr = wid; pr < 98; pr += 4) {
        const int node = pr * 2 + halfB;
        const int hi = node / 14, wi = node - hi * 14;
        float y0 = 0.f, y1 = 0.f;
        #pragma unroll
        for (int kt2 = 0; kt2 < 3; kt2++)
            #pragma unroll
            for (int kh = 0; kh < 3; kh++)
                #pragma unroll
                for (int kw_ = 0; kw_ < 3; kw_++) {
                    const int h2 = hi + kh - 1, w2 = wi + kw_ - 1;
                    const bool ok = ((unsigned)h2 < 14u) && ((unsigned)w2 < 14u);
                    const int n2 = ok ? (h2 * 14 + w2) : 0;
                    const unsigned int u =
                        *(const unsigned int*)&sp[(kt2 * 196 + n2) * 64 + 2 * li];
                    const int ki = (kt2 * 3 + kh) * 3 + kw_;
                    const float w0 = ok ? kwA[ki] : 0.f;
                    const float w1 = ok ? kwB[ki] : 0.f;
                    y0 += bfu2f_lo(u) * w0;
                    y1 += bfu2f_hi(u) * w1;
                }
        // LayerNorm across the 32-lane half (64 channels)
        float s1 = y0 + y1;
        #pragma unroll
        for (int o = 16; o > 0; o >>= 1) s1 += __shfl_xor(s1, o);
        const float mu = s1 * (1.f / 64.f);
        const float d0 = y0 - mu, d1 = y1 - mu;
        float s2 = d0 * d0 + d1 * d1;
        #pragma unroll
        for (int o = 16; o > 0; o >>= 1) s2 += __shfl_xor(s2, o);
        const float inv = rsqrtf(s2 * (1.f / 64.f) + 1e-5f);
        const float o0 = d0 * inv * lw0 + lb0;
        const float o1 = d1 * inv * lw1 + lb1;

        const int n = 1 + t * 196 + node;
        const size_t idx = obase + (size_t)n * HD_;
        *(unsigned int*)&bdst[idx] = pk2bf(o0 * oscale, o1 * oscale);
        if (s == 0) {
            float2 f2; f2.x = o0; f2.y = o1;
            *(float2*)&pqf[idx] = f2;
        }
    }

    // ---- cls token (n = 0), t==0 blocks, wave 0; both halves compute, half A stores ----
    if (t == 0 && wid == 0) {
        const unsigned int u =
            *(const unsigned int*)(qkvb + (size_t)(b * N_) * QKVD + colbase + 2 * li);
        const float y0 = bfu2f_lo(u), y1 = bfu2f_hi(u);
        float s1 = y0 + y1;
        #pragma unroll
        for (int o = 16; o > 0; o >>= 1) s1 += __shfl_xor(s1, o);
        const float mu = s1 * (1.f / 64.f);
        const float d0 = y0 - mu, d1 = y1 - mu;
        float s2 = d0 * d0 + d1 * d1;
        #pragma unroll
        for (int o = 16; o > 0; o >>= 1) s2 += __shfl_xor(s2, o);
        const float inv = rsqrtf(s2 * (1.f / 64.f) + 1e-5f);
        const float o0 = d0 * inv * lw0 + lb0;
        const float o1 = d1 * inv * lw1 + lb1;
        if (halfB == 0) {
            *(unsigned int*)&bdst[obase] = pk2bf(o0 * oscale, o1 * oscale);
            if (s == 0) {
                float2 f2; f2.x = o0; f2.y = o1;
                *(float2*)&pqf[obase] = f2;
            }
        }
    }
}

// ---------------- MFMA flash attention: swapped QK^T + matrix-folded rel bias ----------------
__global__ __launch_bounds__(256) void attn_mfma(
        const short* __restrict__ qb, const short* __restrict__ kb,
        const short* __restrict__ vtb, const short* __restrict__ oneh,
        const float* __restrict__ pqf,
        const float* __restrict__ rpt, const float* __restrict__ rph,
        const float* __restrict__ rpw, short* __restrict__ aoutbf) {
    __shared__ __align__(16) short Kse[64 * 128];  // [key][128d ext] swz256
    __shared__ __align__(16) short VT[64 * 64];    // [d][key] swz128
    __shared__ __align__(16) short QPs[64 * 128];  // Qext swz256; Ps overlays

    const int tid = threadIdx.x;
    const int lane = tid & 63;
    const int wid = tid >> 6;
    const int larow = lane & 15;
    const int lgrp = lane >> 4;

    int bid = (blockIdx.x & 7) * (B_ * HEADS_ * NKT / 8) + (blockIdx.x >> 3);
    const int qt = bid % NKT; bid /= NKT;
    const int h = bid % HEADS_;
    const int b = bid / HEADS_;
    const int q0 = qt * 64;
    const int bh = b * HEADS_ + h;
    const size_t base = (size_t)bh * N_ * HD_;

    short* Qse = QPs;
    short* Ps  = QPs;

    {
        const int row = tid >> 2, seg = tid & 3;
        const int qi = q0 + row;
        short8v v0 = {0,0,0,0,0,0,0,0}, v1 = v0, z = v0;
        if (qi < N_) {
            const short8v* g = (const short8v*)(qb + base + (size_t)qi * HD_ + seg * 16);
            v0 = g[0]; v1 = g[1];
        }
        lds_write8x(Qse, row, seg * 32, v0);
        lds_write8x(Qse, row, seg * 32 + 16, v1);
        lds_write8x(Qse, row, 128 + seg * 32, z);
        lds_write8x(Qse, row, 128 + seg * 32 + 16, z);
    }
    __syncthreads();

    #pragma unroll
    for (int it = 0; it < 9; it++) {
        int flat = it * 256 + tid;
        int row = flat / 36, idx = flat - row * 36;
        int qi = q0 + row;
        bool valid = (qi >= 1 && qi < N_);
        int m = valid ? (qi - 1) : 0;
        int ti = m / 196, rr2 = m - ti * 196;
        int hi = rr2 / 14, wi = rr2 - hi * 14;
        const float* tab;
        if (idx < 8)       tab = rpt + (size_t)(ti - idx + 7) * HD_;
        else if (idx < 22) tab = rph + (size_t)(hi - (idx - 8) + 13) * HD_;
        else               tab = rpw + (size_t)(wi - (idx - 22) + 13) * HD_;
        float acc = 0.f;
        if (valid) {
            const float4* qp = (const float4*)(pqf + base + (size_t)qi * HD_);
            const float4* tp = (const float4*)tab;
            #pragma unroll 4
            for (int dd = 0; dd < 16; dd++) {
                float4 a = qp[dd], t = tp[dd];
                acc += a.x * t.x + a.y * t.y + a.z * t.z + a.w * t.w;
            }
        }
        lds_write1x(Qse, row, 64 + idx, f2bfs(acc));
    }
    if (tid < 64) lds_write1x(Qse, tid, 100, (short)0x3F80);
    __syncthreads();

    short8v bq[4];
    #pragma unroll
    for (int ks = 0; ks < 4; ks++)
        bq[ks] = lds_read8x(Qse, wid * 16 + larow, ks * 64 + lgrp * 16);

    float m_ = -1e30f, l_ = 0.f;
    f32x4 O4[4];
    #pragma unroll
    for (int nf = 0; nf < 4; nf++) O4[nf] = (f32x4){0.f, 0.f, 0.f, 0.f};

    for (int kt = 0; kt < NKT; kt++) {
        __syncthreads();
        {
            const int row = tid >> 2, seg = tid & 3;
            const int jg = kt * 64 + row;
            short8v k0 = {0,0,0,0,0,0,0,0}, k1 = k0;
            if (jg < N_) {
                const short8v* g = (const short8v*)(kb + base + (size_t)jg * HD_ + seg * 16);
                k0 = g[0]; k1 = g[1];
            }
            lds_write8x(Kse, row, seg * 32, k0);
            lds_write8x(Kse, row, seg * 32 + 16, k1);
            const short8v* oh = (const short8v*)(oneh + (size_t)jg * 64 + seg * 16);
            lds_write8x(Kse, row, 128 + seg * 32, oh[0]);
            lds_write8x(Kse, row, 128 + seg * 32 + 16, oh[1]);
            const short8v* gv = (const short8v*)(vtb + ((size_t)bh * HD_ + row) * NPADK + kt * 64 + seg * 16);
            lds_write8(VT, row, seg * 32, gv[0]);
            lds_write8(VT, row, seg * 32 + 16, gv[1]);
        }
        __syncthreads();

        f32x4 s4[4];
        #pragma unroll
        for (int nf = 0; nf < 4; nf++) {
            f32x4 acc = (f32x4){0.f, 0.f, 0.f, 0.f};
            #pragma unroll
            for (int ks = 0; ks < 4; ks++) {
                short8v ak = lds_read8x(Kse, nf * 16 + larow, ks * 64 + lgrp * 16);
                acc = __builtin_amdgcn_mfma_f32_16x16x32_bf16(ak, bq[ks], acc, 0, 0, 0);
            }
            s4[nf] = acc;
        }

        float rm = -1e30f;
        #pragma unroll
        for (int nf = 0; nf < 4; nf++)
            #pragma unroll
            for (int r = 0; r < 4; r++) rm = fmaxf(rm, s4[nf][r]);
        rm = fmaxf(rm, __shfl_xor(rm, 16));
        rm = fmaxf(rm, __shfl_xor(rm, 32));
        float mn = fmaxf(m_, rm);
        float fac = __expf(m_ - mn);
        m_ = mn;
        float p[4][4];
        float ps = 0.f;
        #pragma unroll
        for (int nf = 0; nf < 4; nf++)
            #pragma unroll
            for (int r = 0; r < 4; r++) {
                float e = __expf(s4[nf][r] - mn);
                p[nf][r] = e; ps += e;
            }
        ps += __shfl_xor(ps, 16);
        ps += __shfl_xor(ps, 32);
        l_ = l_ * fac + ps;

        const int prow = wid * 16 + larow;
        #pragma unroll
        for (int nf = 0; nf < 4; nf++)
            lds_writeP(Ps, prow, nf * 32 + lgrp * 8,
                       pk2bf(p[nf][0], p[nf][1]), pk2bf(p[nf][2], p[nf][3]));

        float facr[4];
        #pragma unroll
        for (int r = 0; r < 4; r++) facr[r] = __shfl(fac, lgrp * 4 + r);
        #pragma unroll
        for (int nf = 0; nf < 4; nf++)
            #pragma unroll
            for (int r = 0; r < 4; r++) O4[nf][r] *= facr[r];

        short8v ap[2];
        ap[0] = lds_read8(Ps, prow, lgrp * 16);
        ap[1] = lds_read8(Ps, prow, 64 + lgrp * 16);
        #pragma unroll
        for (int nf = 0; nf < 4; nf++) {
            #pragma unroll
            for (int ks = 0; ks < 2; ks++) {
                short8v bv2 = lds_read8(VT, nf * 16 + larow, ks * 64 + lgrp * 16);
                O4[nf] = __builtin_amdgcn_mfma_f32_16x16x32_bf16(ap[ks], bv2, O4[nf], 0, 0, 0);
            }
        }
    }

    float linv[4];
    #pragma unroll
    for (int r = 0; r < 4; r++) linv[r] = 1.f / __shfl(l_, lgrp * 4 + r);
    #pragma unroll
    for (int nf = 0; nf < 4; nf++) {
        const int d = nf * 16 + larow;
        #pragma unroll
        for (int r = 0; r < 4; r++) {
            const int rowL = wid * 16 + lgrp * 4 + r;
            const int qi = q0 + rowL;
            if (qi < N_) {
                float o = O4[nf][r] * linv[r];
                if (qi > 0) o += pqf[base + (size_t)qi * HD_ + d];
                aoutbf[(size_t)(b * N_ + qi) * (HEADS_ * HD_) + h * HD_ + d] = f2bfs(o);
            }
        }
    }
}

extern "C" void kernel_launch(void* const* d_in, const int* in_sizes, int n_in,
                              void* d_out, int out_size, void* d_ws, size_t ws_size,
                              hipStream_t stream) {
    const float* x    = (const float*)d_in[0];
    const float* Wqkv = (const float*)d_in[1];
    const float* bqkv = (const float*)d_in[2];
    const float* kq   = (const float*)d_in[3];
    const float* kk   = (const float*)d_in[4];
    const float* kv   = (const float*)d_in[5];
    const float* nqw  = (const float*)d_in[6];
    const float* nqb  = (const float*)d_in[7];
    const float* nkw  = (const float*)d_in[8];
    const float* nkb  = (const float*)d_in[9];
    const float* nvw  = (const float*)d_in[10];
    const float* nvb  = (const float*)d_in[11];
    const float* rpt  = (const float*)d_in[12];
    const float* rph  = (const float*)d_in[13];
    const float* rpw  = (const float*)d_in[14];
    const float* Wproj= (const float*)d_in[15];
    const float* bproj= (const float*)d_in[16];
    float* out = (float*)d_out;

    const size_t qkv_elems  = (size_t)M_ * QKVD;                  // 14.46M
    const size_t pool_elems = (size_t)B_ * HEADS_ * N_ * HD_;     // 4.82M
    short* qkvb = (short*)d_ws;                    // [M_][QKVD] bf16, 28.9 MB
    float* pqf  = (float*)(qkvb + qkv_elems);      // f32 pooled q, 19.3 MB
    short* qbb  = (short*)(pqf + pool_elems);      // bf16 q(*0.125)/k/v
    short* kbb  = qbb + pool_elems;
    short* vbb  = kbb + pool_elems;
    short* abuf = vbb + pool_elems;                // [MPAD][768] bf16
    short* w1t  = abuf + (size_t)MPAD * IND;       // [2304][768] bf16
    short* vtb  = w1t + (size_t)QKVD * IND;        // [48][64][1600] bf16
    short* oneh = vtb + (size_t)B_ * HEADS_ * HD_ * NPADK;  // [1600][64] bf16

    // GEMM1: qkv(bf16) = x @ Wqkv + b
    f32_to_bf16_rows<<<MPAD, 256, 0, stream>>>(x, abuf, M_, IND);
    transpose_f32_bf16<<<dim3(QKVD / 32, IND / 32), 256, 0, stream>>>(Wqkv, w1t, IND, QKVD);
    build_onehot<<<NPADK, 64, 0, stream>>>(oneh);
    gemm_mfma<short><<<dim3(QKVD / 128, MPAD / 128), 256, 0, stream>>>(abuf, w1t, bqkv, qkvb, M_, QKVD, IND);

    pool_ln<<<PBLK, 256, 0, stream>>>(qkvb, kq, kk, kv,
        nqw, nqb, nkw, nkb, nvw, nvb, pqf, qbb, kbb, vbb);

    transpose_v_pad<<<B_ * HEADS_ * NKT, 256, 0, stream>>>(vbb, vtb);

    attn_mfma<<<B_ * HEADS_ * NKT, 256, 0, stream>>>(qbb, kbb, vtb, oneh, pqf, rpt, rph, rpw, abuf);

    // GEMM2: out(f32) = attn_out @ Wproj + b
    transpose_f32_bf16<<<dim3(IND / 32, IND / 32), 256, 0, stream>>>(Wproj, w1t, IND, IND);
    gemm_mfma<float><<<dim3(IND / 128, MPAD / 128), 256, 0, stream>>>(abuf, w1t, bproj, out, M_, IND, IND);
}